// Round 14
// baseline (2144.840 us; speedup 1.0000x reference)
//
#include <hip/hip_runtime.h>
#include <math.h>

#define Bz 64
#define Tz 12000
#define Pz 50
#define Dz 200
#define Lz 12
#define Hz 10
#define HDz 20
#define FFz 800
#define Nz 240
#define Sz 241
#define Sp 256                // padded seq stride
#define NRDz 482
#define NCz 1000
#define BS (Bz * Sz)          // 15424 valid rows
#define Mp (Bz * Sp)          // 16384 padded rows
#define Kp 224                // K=200 padded to 7*32
#define PEM (Bz * Nz)         // 15360 patch rows
#define SCALEq 0.22360679774997896f
#define LOG2E 1.4426950408889634f
#define SCALE2f (SCALEq * LOG2E)
#define BIASL 655360          // shorts per layer of bias table

typedef __attribute__((ext_vector_type(8))) short bf16x8;
typedef __attribute__((ext_vector_type(4))) float f32x4;

static __device__ __forceinline__ short f2b(float f) {
    unsigned u = __float_as_uint(f);
    unsigned r = (u + 0x7fffu + ((u >> 16) & 1u)) >> 16;
    return (short)r;
}
static __device__ __forceinline__ float b2f(short v) {
    return __uint_as_float(((unsigned)(unsigned short)v) << 16);
}
static __device__ __forceinline__ uint2 pk4(float a, float b, float c, float d) {
    uint2 r;
    asm("v_cvt_pk_bf16_f32 %0, %1, %2" : "=v"(r.x) : "v"(a), "v"(b));
    asm("v_cvt_pk_bf16_f32 %0, %1, %2" : "=v"(r.y) : "v"(c), "v"(d));
    return r;
}
static __device__ __forceinline__ float frcp(float x) {
    float r;
    asm("v_rcp_f32 %0, %1" : "=v"(r) : "v"(x));
    return r;
}
static __device__ __forceinline__ float gelu_f(float v) {
    float u = v * (0.7978845608f + 0.03567740814f * v * v);
    float e = exp2f(2.885390082f * u);
    return v * e * frcp(e + 1.f);
}
static __device__ __forceinline__ void gll16(const void* g, void* l) {
    __builtin_amdgcn_global_load_lds((const __attribute__((address_space(1))) unsigned*)g,
                                     (__attribute__((address_space(3))) unsigned*)l, 16, 0, 0);
}

// ---------------- f32 [L][N][K] -> bf16 [L][Npad][Kpad] zero-padded ----------------
__global__ void cvt_pad_k(const float* __restrict__ in, short* __restrict__ out,
                          int N, int K, int Npad, int Kpad, int total) {
    int i = blockIdx.x * 256 + threadIdx.x;
    if (i >= total) return;
    int pk = Npad * Kpad;
    int l = i / pk;
    int r = i - l * pk;
    int n = r / Kpad;
    int k = r - n * Kpad;
    float v = (n < N && k < K) ? in[((size_t)l * N + n) * K + k] : 0.f;
    out[i] = f2b(v);
}

// ---------------- x -> bf16 patches [15360][64] ----------------
__global__ void xcvt_k(const float* __restrict__ x, short* __restrict__ xb) {
    int i = blockIdx.x * 256 + threadIdx.x;
    int m = i >> 6, k = i & 63;
    int b = m / Nz, j = m - b * Nz;
    xb[i] = (k < Pz) ? f2b(x[(size_t)b * Tz + j * Pz + k]) : 0;
}

// ---------------- cls rows ----------------
__global__ void cls_k(const float* __restrict__ cls, const float* __restrict__ pos,
                      float* __restrict__ tok) {
    int b = blockIdx.x, d = threadIdx.x;
    if (d < Dz) tok[(size_t)b * Sp * Dz + d] = cls[d] + pos[d];
}

// ---------------- layernorm (initial ln1 only) ----------------
__global__ void ln_k(const float* __restrict__ in, short* __restrict__ out,
                     const float* __restrict__ sc, const float* __restrict__ bi) {
    int wave = threadIdx.x >> 6, lane = threadIdx.x & 63;
    int row = blockIdx.x * 4 + wave;
    if ((row & 255) >= Sz) return;
    const float* x = in + (size_t)row * Dz;
    float v[4];
    float sum = 0.f;
    #pragma unroll
    for (int i = 0; i < 4; ++i) {
        int d = lane + 64 * i;
        v[i] = (d < Dz) ? x[d] : 0.f;
        sum += v[i];
    }
    #pragma unroll
    for (int off = 32; off; off >>= 1) sum += __shfl_xor(sum, off);
    float mean = sum * (1.f / Dz);
    float var = 0.f;
    #pragma unroll
    for (int i = 0; i < 4; ++i) {
        int d = lane + 64 * i;
        if (d < Dz) { float t = v[i] - mean; var += t * t; }
    }
    #pragma unroll
    for (int off = 32; off; off >>= 1) var += __shfl_xor(var, off);
    var *= (1.f / Dz);
    float rstd = rsqrtf(var + 1e-6f);
    short* o = out + (size_t)row * Kp;
    #pragma unroll
    for (int i = 0; i < 4; ++i) {
        int d = lane + 64 * i;
        if (d < Dz) o[d] = f2b((v[i] - mean) * rstd * sc[d] + bi[d]);
        else if (d < Kp) o[d] = 0;
    }
}

// ---------------- bias precompute (ALL layers), swapped-fragment order ----------------
__global__ void bias_pre4_k(const float* __restrict__ tabs, short* __restrict__ bp) {
    int l = blockIdx.y;
    int tid = blockIdx.x * 256 + threadIdx.x;
    const float* tab = tabs + (size_t)l * NRDz * Hz;
    int lane = tid & 63;
    int mi = (tid >> 6) & 1;
    int w  = (tid >> 7) & 3;
    int qb = (tid >> 9) & 1;
    int nj = (tid >> 10) & 3;
    int kc = (tid >> 12) & 3;
    int h  = tid >> 14;
    int q  = qb * 128 + w * 32 + mi * 16 + (lane & 15);
    int k0 = kc * 64 + nj * 16 + 4 * (lane >> 4);
    short4 o;
    #pragma unroll
    for (int r = 0; r < 4; ++r) {
        int k = k0 + r;
        float v;
        if (q > Nz || k > Nz) v = -1e30f;
        else if (k == 0)      v = (q == 0) ? tab[481 * Hz + h] : tab[480 * Hz + h];
        else if (q == 0)      v = tab[479 * Hz + h];
        else                  v = tab[(q - k + 239) * Hz + h];
        ((short*)&o)[r] = f2b(v * LOG2E);
    }
    *(short4*)(bp + (size_t)l * BIASL + (size_t)tid * 4) = o;
}

// ---------------- MFMA GEMM v6 (used for patch embed, qkv layer-0, head) ----------
// MODE 0: f32 +bias (head)   MODE 1: qkv -> Qb/Kb/Vtb   MODE 4: patch embed
template <int MODE, int BN2, int BM2>
__global__ __launch_bounds__(256) void gemm6_k(
        const short* __restrict__ A, const short* __restrict__ W,
        const float* __restrict__ bias, const float* __restrict__ bias2,
        const float* __restrict__ res, void* __restrict__ outv,
        short* __restrict__ qo, short* __restrict__ ko, short* __restrict__ vo,
        int M, int Nreal, int K, int strideA, int ldo, int gridx, int gridy) {
    constexpr int NJ = BN2 / 32;
    constexpr int MI = BM2 / 32;
    constexpr int AISS = BM2 / 64;
    constexpr int BISS = BN2 / 64;
    __shared__ short As[2][BM2 * 32];
    __shared__ short Bs[2][BN2 * 32];
    const int t = threadIdx.x;
    const int lane = t & 63, w = t >> 6;
    const int l15 = lane & 15, lg = lane >> 4;
    const int wm = w & 1, wn = w >> 1;

    int bx, by;
    {
        int wg = blockIdx.x;
        if ((gridy & 7) == 0) {
            int xcd = wg & 7, j = wg >> 3;
            bx = j % gridx;
            by = (j / gridx) * 8 + xcd;
        } else {
            bx = wg % gridx;
            by = wg / gridx;
        }
    }
    const int row0 = by * BM2, col0 = bx * BN2;
    const int xsw = (l15 >> 1) & 3;

    f32x4 acc[MI][NJ];
    #pragma unroll
    for (int mi = 0; mi < MI; ++mi)
        #pragma unroll
        for (int nj = 0; nj < NJ; ++nj) {
            f32x4 z = {0.f, 0.f, 0.f, 0.f};
            acc[mi][nj] = z;
        }

    const int nk = K >> 5;

    auto stage = [&](int buf, int kt) {
        const int k0 = kt * 32;
        #pragma unroll
        for (int i = 0; i < AISS; ++i) {
            int c = (w * AISS + i) * 64 + lane;
            int r = c >> 2, q = c & 3;
            const short* gp = A + (size_t)(row0 + r) * strideA + k0 + ((q ^ ((r >> 1) & 3)) * 8);
            gll16(gp, As[buf] + (w * AISS + i) * 512);
        }
        #pragma unroll
        for (int i = 0; i < BISS; ++i) {
            int c = (w * BISS + i) * 64 + lane;
            int r = c >> 2, q = c & 3;
            const short* gp = W + (size_t)(col0 + r) * K + k0 + ((q ^ ((r >> 1) & 3)) * 8);
            gll16(gp, Bs[buf] + (w * BISS + i) * 512);
        }
    };

    stage(0, 0);
    __syncthreads();
    for (int kt = 0; kt < nk; ++kt) {
        const int cur = kt & 1;
        if (kt + 1 < nk) stage(cur ^ 1, kt + 1);
        bf16x8 bfr[NJ], afr[MI];
        #pragma unroll
        for (int nj = 0; nj < NJ; ++nj)
            bfr[nj] = *(const bf16x8*)(Bs[cur] + (wn * (BN2 / 2) + nj * 16 + l15) * 32 + ((lg ^ xsw) * 8));
        #pragma unroll
        for (int mi = 0; mi < MI; ++mi)
            afr[mi] = *(const bf16x8*)(As[cur] + (wm * (BM2 / 2) + mi * 16 + l15) * 32 + ((lg ^ xsw) * 8));
        #pragma unroll
        for (int mi = 0; mi < MI; ++mi)
            #pragma unroll
            for (int nj = 0; nj < NJ; ++nj)
                acc[mi][nj] = __builtin_amdgcn_mfma_f32_16x16x32_bf16(afr[mi], bfr[nj], acc[mi][nj], 0, 0, 0);
        __syncthreads();
    }

    #pragma unroll
    for (int mi = 0; mi < MI; ++mi) {
        #pragma unroll
        for (int nj = 0; nj < NJ; ++nj) {
            int n = col0 + wn * (BN2 / 2) + nj * 16 + l15;
            if (n >= Nreal) continue;
            if (MODE == 1) {
                int which = n >= 400 ? 2 : (n >= 200 ? 1 : 0);
                int hd = n - which * 200;
                int h = hd / 20, d = hd - h * 20;
                int m0 = row0 + wm * (BM2 / 2) + mi * 16 + 4 * lg;
                int b = m0 >> 8, s0 = m0 & 255;
                size_t base = (size_t)(b * Hz + h) * 8192;
                if (which == 2) {
                    short4 o4;
                    float vb = bias2[hd];
                    #pragma unroll
                    for (int r = 0; r < 4; ++r)
                        ((short*)&o4)[r] = f2b(acc[mi][nj][r] + vb);
                    *(short4*)(vo + base + d * 256 + (s0 ^ ((d & 7) << 3))) = o4;
                } else if (which == 0) {
                    float qb = bias[hd];
                    #pragma unroll
                    for (int r = 0; r < 4; ++r)
                        qo[base + (s0 + r) * 32 + d] = f2b((acc[mi][nj][r] + qb) * SCALE2f);
                } else {
                    #pragma unroll
                    for (int r = 0; r < 4; ++r) {
                        int s = s0 + r;
                        ko[base + s * 32 + (((d >> 3) ^ ((s >> 1) & 3)) * 8) + (d & 7)] = f2b(acc[mi][nj][r]);
                    }
                }
            } else if (MODE == 4) {
                #pragma unroll
                for (int r = 0; r < 4; ++r) {
                    int m = row0 + wm * (BM2 / 2) + mi * 16 + 4 * lg + r;
                    int bb = m / Nz, j = m - bb * Nz;
                    size_t trow = (size_t)bb * Sp + j + 1;
                    ((float*)outv)[trow * ldo + n] =
                        acc[mi][nj][r] + bias[n] + res[(size_t)(j + 1) * Dz + n];
                }
            } else {
                #pragma unroll
                for (int r = 0; r < 4; ++r) {
                    int m = row0 + wm * (BM2 / 2) + mi * 16 + 4 * lg + r;
                    if (m >= M) continue;
                    size_t off = (size_t)m * ldo + n;
                    ((float*)outv)[off] = acc[mi][nj][r] + bias[n];
                }
            }
        }
    }
}

// ---------------- fused layer back-half: proj+res+LN2+fc1+gelu+fc2+res+LN1'+qkv' -----
// 1024 blocks x 16 rows. LDS ~71 KB -> 2 blocks/CU.
__global__ __launch_bounds__(256) void mlp_fused_k(
        const short* __restrict__ xbuf, float* __restrict__ tok,
        const short* __restrict__ wp, const float* __restrict__ pb,
        const float* __restrict__ l2s, const float* __restrict__ l2b,
        const short* __restrict__ w1, const float* __restrict__ b1,
        const short* __restrict__ w2, const float* __restrict__ b2v,
        const float* __restrict__ l1s, const float* __restrict__ l1b,
        const short* __restrict__ wq, const float* __restrict__ qbi,
        const float* __restrict__ vbi,
        short* __restrict__ Qo, short* __restrict__ Ko, short* __restrict__ Vo,
        int doqkv) {
    __shared__ short As2[2][512];
    __shared__ short Bs2[2][8192];
    __shared__ short A2[16 * 232];
    __shared__ short midl[16 * 904];
    __shared__ float lnred[16][4];
    const int t = threadIdx.x;
    const int lane = t & 63, w = t >> 6;
    const int l15 = lane & 15, lg = lane >> 4;
    const int xsw = (l15 >> 1) & 3;
    const int m0 = blockIdx.x * 16;
    const int mr0 = 4 * lg;

    // ========== Phase A: proj, C[16][256] ==========
    f32x4 acc[4];
    #pragma unroll
    for (int nj = 0; nj < 4; ++nj) { f32x4 z = {0.f, 0.f, 0.f, 0.f}; acc[nj] = z; }
    auto stageA = [&](int buf, int kt) {
        int k0 = kt * 32;
        if (w == 0) {
            int r = lane >> 2, q = lane & 3;
            gll16(xbuf + (size_t)(m0 + r) * Kp + k0 + ((q ^ ((r >> 1) & 3)) * 8), As2[buf]);
        }
        #pragma unroll
        for (int i = 0; i < 4; ++i) {
            int idx = w * 4 + i;
            int c = idx * 64 + lane;
            int r = c >> 2, q = c & 3;
            gll16(wp + (size_t)r * Kp + k0 + ((q ^ ((r >> 1) & 3)) * 8), Bs2[buf] + idx * 512);
        }
    };
    stageA(0, 0);
    __syncthreads();
    for (int kt = 0; kt < 7; ++kt) {
        int cur = kt & 1;
        if (kt + 1 < 7) stageA(cur ^ 1, kt + 1);
        bf16x8 afr = *(const bf16x8*)(As2[cur] + l15 * 32 + ((lg ^ xsw) * 8));
        #pragma unroll
        for (int nj = 0; nj < 4; ++nj) {
            bf16x8 bfr = *(const bf16x8*)(Bs2[cur] + (w * 64 + nj * 16 + l15) * 32 + ((lg ^ xsw) * 8));
            acc[nj] = __builtin_amdgcn_mfma_f32_16x16x32_bf16(afr, bfr, acc[nj], 0, 0, 0);
        }
        __syncthreads();
    }
    // epilogue A: +bias +res -> ptok; LN2 -> A2
    float ptok[4][4];
    {
        float rs[4] = {0.f, 0.f, 0.f, 0.f};
        #pragma unroll
        for (int nj = 0; nj < 4; ++nj) {
            int n = w * 64 + nj * 16 + l15;
            bool val = n < Dz;
            float bv = val ? pb[n] : 0.f;
            #pragma unroll
            for (int r = 0; r < 4; ++r) {
                float z = 0.f;
                if (val) z = acc[nj][r] + bv + tok[(size_t)(m0 + mr0 + r) * Dz + n];
                ptok[nj][r] = z;
                rs[r] += z;
            }
        }
        #pragma unroll
        for (int r = 0; r < 4; ++r)
            #pragma unroll
            for (int msk = 1; msk <= 8; msk <<= 1) rs[r] += __shfl_xor(rs[r], msk);
        if (l15 == 0)
            #pragma unroll
            for (int r = 0; r < 4; ++r) lnred[mr0 + r][w] = rs[r];
        __syncthreads();
        float mean[4];
        #pragma unroll
        for (int r = 0; r < 4; ++r)
            mean[r] = (lnred[mr0 + r][0] + lnred[mr0 + r][1] + lnred[mr0 + r][2] + lnred[mr0 + r][3]) * (1.f / Dz);
        __syncthreads();
        float vs[4] = {0.f, 0.f, 0.f, 0.f};
        #pragma unroll
        for (int nj = 0; nj < 4; ++nj) {
            int n = w * 64 + nj * 16 + l15;
            if (n < Dz)
                #pragma unroll
                for (int r = 0; r < 4; ++r) { float d = ptok[nj][r] - mean[r]; vs[r] += d * d; }
        }
        #pragma unroll
        for (int r = 0; r < 4; ++r)
            #pragma unroll
            for (int msk = 1; msk <= 8; msk <<= 1) vs[r] += __shfl_xor(vs[r], msk);
        if (l15 == 0)
            #pragma unroll
            for (int r = 0; r < 4; ++r) lnred[mr0 + r][w] = vs[r];
        __syncthreads();
        float rstd[4];
        #pragma unroll
        for (int r = 0; r < 4; ++r)
            rstd[r] = rsqrtf((lnred[mr0 + r][0] + lnred[mr0 + r][1] + lnred[mr0 + r][2] + lnred[mr0 + r][3]) * (1.f / Dz) + 1e-6f);
        #pragma unroll
        for (int nj = 0; nj < 4; ++nj) {
            int n = w * 64 + nj * 16 + l15;
            if (n < Dz) {
                float sn = l2s[n], bn = l2b[n];
                #pragma unroll
                for (int r = 0; r < 4; ++r) {
                    tok[(size_t)(m0 + mr0 + r) * Dz + n] = ptok[nj][r];
                    A2[(mr0 + r) * 232 + n] = f2b((ptok[nj][r] - mean[r]) * rstd[r] * sn + bn);
                }
            } else if (n < 232) {
                #pragma unroll
                for (int r = 0; r < 4; ++r) A2[(mr0 + r) * 232 + n] = 0;
            }
        }
    }
    __syncthreads();

    // ========== Phase B: fc1 -> midl (7 chunks x 128 cols) ==========
    #pragma unroll 1
    for (int nc = 0; nc < 7; ++nc) {
        f32x4 acc2[2];
        #pragma unroll
        for (int nj = 0; nj < 2; ++nj) { f32x4 z = {0.f, 0.f, 0.f, 0.f}; acc2[nj] = z; }
        auto stageB = [&](int buf, int kt) {
            int k0 = kt * 32;
            #pragma unroll
            for (int i = 0; i < 2; ++i) {
                int idx = w * 2 + i;
                int c = idx * 64 + lane;
                int r = c >> 2, q = c & 3;
                gll16(w1 + (size_t)(nc * 128 + r) * Kp + k0 + ((q ^ ((r >> 1) & 3)) * 8), Bs2[buf] + idx * 512);
            }
        };
        stageB(0, 0);
        __syncthreads();
        for (int kt = 0; kt < 7; ++kt) {
            int cur = kt & 1;
            if (kt + 1 < 7) stageB(cur ^ 1, kt + 1);
            bf16x8 afr = *(const bf16x8*)(A2 + l15 * 232 + kt * 32 + lg * 8);
            #pragma unroll
            for (int nj = 0; nj < 2; ++nj) {
                bf16x8 bfr = *(const bf16x8*)(Bs2[cur] + (w * 32 + nj * 16 + l15) * 32 + ((lg ^ xsw) * 8));
                acc2[nj] = __builtin_amdgcn_mfma_f32_16x16x32_bf16(afr, bfr, acc2[nj], 0, 0, 0);
            }
            __syncthreads();
        }
        #pragma unroll
        for (int nj = 0; nj < 2; ++nj) {
            int col = nc * 128 + w * 32 + nj * 16 + l15;
            float bv = (col < FFz) ? b1[col] : 0.f;
            #pragma unroll
            for (int r = 0; r < 4; ++r)
                midl[(mr0 + r) * 904 + col] = f2b(gelu_f(acc2[nj][r] + bv));
        }
    }
    __syncthreads();

    // ========== Phase C: fc2, C[16][256], K=800 from midl ==========
    f32x4 acc3[4];
    #pragma unroll
    for (int nj = 0; nj < 4; ++nj) { f32x4 z = {0.f, 0.f, 0.f, 0.f}; acc3[nj] = z; }
    auto stageC = [&](int buf, int kt) {
        int k0 = kt * 32;
        #pragma unroll
        for (int i = 0; i < 4; ++i) {
            int idx = w * 4 + i;
            int c = idx * 64 + lane;
            int r = c >> 2, q = c & 3;
            gll16(w2 + (size_t)r * FFz + k0 + ((q ^ ((r >> 1) & 3)) * 8), Bs2[buf] + idx * 512);
        }
    };
    stageC(0, 0);
    __syncthreads();
    for (int kt = 0; kt < 25; ++kt) {
        int cur = kt & 1;
        if (kt + 1 < 25) stageC(cur ^ 1, kt + 1);
        bf16x8 afr = *(const bf16x8*)(midl + l15 * 904 + kt * 32 + lg * 8);
        #pragma unroll
        for (int nj = 0; nj < 4; ++nj) {
            bf16x8 bfr = *(const bf16x8*)(Bs2[cur] + (w * 64 + nj * 16 + l15) * 32 + ((lg ^ xsw) * 8));
            acc3[nj] = __builtin_amdgcn_mfma_f32_16x16x32_bf16(afr, bfr, acc3[nj], 0, 0, 0);
        }
        __syncthreads();
    }
    // epilogue C: +bias +ptok residual -> tok; optional LN1-next + qkv-next
    float rs2[4] = {0.f, 0.f, 0.f, 0.f};
    #pragma unroll
    for (int nj = 0; nj < 4; ++nj) {
        int n = w * 64 + nj * 16 + l15;
        bool val = n < Dz;
        float bv = val ? b2v[n] : 0.f;
        #pragma unroll
        for (int r = 0; r < 4; ++r) {
            float z = 0.f;
            if (val) {
                z = acc3[nj][r] + bv + ptok[nj][r];
                tok[(size_t)(m0 + mr0 + r) * Dz + n] = z;
            }
            ptok[nj][r] = z;
            rs2[r] += z;
        }
    }
    if (doqkv) {
        #pragma unroll
        for (int r = 0; r < 4; ++r)
            #pragma unroll
            for (int msk = 1; msk <= 8; msk <<= 1) rs2[r] += __shfl_xor(rs2[r], msk);
        if (l15 == 0)
            #pragma unroll
            for (int r = 0; r < 4; ++r) lnred[mr0 + r][w] = rs2[r];
        __syncthreads();
        float mean2[4];
        #pragma unroll
        for (int r = 0; r < 4; ++r)
            mean2[r] = (lnred[mr0 + r][0] + lnred[mr0 + r][1] + lnred[mr0 + r][2] + lnred[mr0 + r][3]) * (1.f / Dz);
        __syncthreads();
        float vs2[4] = {0.f, 0.f, 0.f, 0.f};
        #pragma unroll
        for (int nj = 0; nj < 4; ++nj) {
            int n = w * 64 + nj * 16 + l15;
            if (n < Dz)
                #pragma unroll
                for (int r = 0; r < 4; ++r) { float d = ptok[nj][r] - mean2[r]; vs2[r] += d * d; }
        }
        #pragma unroll
        for (int r = 0; r < 4; ++r)
            #pragma unroll
            for (int msk = 1; msk <= 8; msk <<= 1) vs2[r] += __shfl_xor(vs2[r], msk);
        if (l15 == 0)
            #pragma unroll
            for (int r = 0; r < 4; ++r) lnred[mr0 + r][w] = vs2[r];
        __syncthreads();
        float rst2[4];
        #pragma unroll
        for (int r = 0; r < 4; ++r)
            rst2[r] = rsqrtf((lnred[mr0 + r][0] + lnred[mr0 + r][1] + lnred[mr0 + r][2] + lnred[mr0 + r][3]) * (1.f / Dz) + 1e-6f);
        #pragma unroll
        for (int nj = 0; nj < 4; ++nj) {
            int n = w * 64 + nj * 16 + l15;
            if (n < Dz) {
                float sn = l1s[n], bn = l1b[n];
                #pragma unroll
                for (int r = 0; r < 4; ++r)
                    A2[(mr0 + r) * 232 + n] = f2b((ptok[nj][r] - mean2[r]) * rst2[r] * sn + bn);
            } else if (n < 232) {
                #pragma unroll
                for (int r = 0; r < 4; ++r) A2[(mr0 + r) * 232 + n] = 0;
            }
        }
        __syncthreads();

        // ========== Phase D: qkv-next (5 chunks x 128 cols) ==========
        const int bb = m0 >> 8, s0b = (m0 & 255) + mr0;
        #pragma unroll 1
        for (int nc = 0; nc < 5; ++nc) {
            f32x4 acc4[2];
            #pragma unroll
            for (int nj = 0; nj < 2; ++nj) { f32x4 z = {0.f, 0.f, 0.f, 0.f}; acc4[nj] = z; }
            auto stageD = [&](int buf, int kt) {
                int k0 = kt * 32;
                #pragma unroll
                for (int i = 0; i < 2; ++i) {
                    int idx = w * 2 + i;
                    int c = idx * 64 + lane;
                    int r = c >> 2, q = c & 3;
                    gll16(wq + (size_t)(nc * 128 + r) * Kp + k0 + ((q ^ ((r >> 1) & 3)) * 8), Bs2[buf] + idx * 512);
                }
            };
            stageD(0, 0);
            __syncthreads();
            for (int kt = 0; kt < 7; ++kt) {
                int cur = kt & 1;
                if (kt + 1 < 7) stageD(cur ^ 1, kt + 1);
                bf16x8 afr = *(const bf16x8*)(A2 + l15 * 232 + kt * 32 + lg * 8);
                #pragma unroll
                for (int nj = 0; nj < 2; ++nj) {
                    bf16x8 bfr = *(const bf16x8*)(Bs2[cur] + (w * 32 + nj * 16 + l15) * 32 + ((lg ^ xsw) * 8));
                    acc4[nj] = __builtin_amdgcn_mfma_f32_16x16x32_bf16(afr, bfr, acc4[nj], 0, 0, 0);
                }
                __syncthreads();
            }
            #pragma unroll
            for (int nj = 0; nj < 2; ++nj) {
                int n = nc * 128 + w * 32 + nj * 16 + l15;
                if (n >= 600) continue;
                int which = n >= 400 ? 2 : (n >= 200 ? 1 : 0);
                int hd = n - which * 200;
                int h = hd / 20, d = hd - h * 20;
                size_t base = (size_t)(bb * Hz + h) * 8192;
                if (which == 2) {
                    short4 o4;
                    float vb = vbi[hd];
                    #pragma unroll
                    for (int r = 0; r < 4; ++r)
                        ((short*)&o4)[r] = f2b(acc4[nj][r] + vb);
                    *(short4*)(Vo + base + d * 256 + (s0b ^ ((d & 7) << 3))) = o4;
                } else if (which == 0) {
                    float qb = qbi[hd];
                    #pragma unroll
                    for (int r = 0; r < 4; ++r)
                        Qo[base + (s0b + r) * 32 + d] = f2b((acc4[nj][r] + qb) * SCALE2f);
                } else {
                    #pragma unroll
                    for (int r = 0; r < 4; ++r) {
                        int s = s0b + r;
                        Ko[base + s * 32 + (((d >> 3) ^ ((s >> 1) & 3)) * 8) + (d & 7)] = f2b(acc4[nj][r]);
                    }
                }
            }
        }
    }
}

// ---------------- MFMA attention v5 (unchanged) ----------------
#define PLD 72
__global__ __launch_bounds__(256) void attn5_k(const short* __restrict__ Qb,
                                               const short* __restrict__ Kb,
                                               const short* __restrict__ Vtb,
                                               const short* __restrict__ biasC,
                                               short* __restrict__ o) {
    const int blk = blockIdx.x;
    const int qb = blk & 1;
    const int bh = blk >> 1;
    const int b = bh / Hz, h = bh - b * Hz;
    __shared__ short Ks[8192];
    __shared__ short Vt[8192];
    __shared__ short Pl[4][32 * PLD];
    const int t = threadIdx.x;
    const int lane = t & 63, w = t >> 6;
    const int l15 = lane & 15, lg = lane >> 4;

    const short* kbh = Kb + (size_t)bh * 8192;
    const short* vbh = Vtb + (size_t)bh * 8192;
    #pragma unroll
    for (int i = 0; i < 4; ++i) {
        int j = w * 4 + i;
        gll16(kbh + (size_t)(j * 64 + lane) * 8, Ks + j * 512);
        gll16(vbh + (size_t)(j * 64 + lane) * 8, Vt + j * 512);
    }
    bf16x8 qfrag[2];
    const short* qbh = Qb + (size_t)bh * 8192;
    #pragma unroll
    for (int mi = 0; mi < 2; ++mi) {
        int qrow = qb * 128 + w * 32 + mi * 16 + l15;
        qfrag[mi] = *(const bf16x8*)(qbh + qrow * 32 + lg * 8);
    }
    const short* bpp = biasC + 4 * (size_t)(lane + 128 * w + 512 * qb + 16384 * h);
    __syncthreads();

    f32x4 O[2][2];
    float mrow[2] = {-1e30f, -1e30f};
    float lrow[2] = {0.f, 0.f};
    {
        f32x4 z = {0.f, 0.f, 0.f, 0.f};
        O[0][0] = z; O[0][1] = z; O[1][0] = z; O[1][1] = z;
    }
    const int xsw = (l15 >> 1) & 3;

    #pragma unroll 1
    for (int kc = 0; kc < 4; ++kc) {
        bf16x8 kf[4];
        #pragma unroll
        for (int nj = 0; nj < 4; ++nj)
            kf[nj] = *(const bf16x8*)(Ks + (kc * 64 + nj * 16 + l15) * 32 + ((lg ^ xsw) * 8));
        f32x4 s[2][4];
        __builtin_amdgcn_s_setprio(1);
        #pragma unroll
        for (int mi = 0; mi < 2; ++mi)
            #pragma unroll
            for (int nj = 0; nj < 4; ++nj) {
                f32x4 z = {0.f, 0.f, 0.f, 0.f};
                s[mi][nj] = __builtin_amdgcn_mfma_f32_16x16x32_bf16(kf[nj], qfrag[mi], z, 0, 0, 0);
            }
        __builtin_amdgcn_s_setprio(0);
        const short* bkc = bpp + kc * 16384;
        #pragma unroll
        for (int mi = 0; mi < 2; ++mi)
            #pragma unroll
            for (int nj = 0; nj < 4; ++nj) {
                short4 bp4 = *(const short4*)(bkc + nj * 4096 + mi * 256);
                s[mi][nj][0] += b2f(bp4.x);
                s[mi][nj][1] += b2f(bp4.y);
                s[mi][nj][2] += b2f(bp4.z);
                s[mi][nj][3] += b2f(bp4.w);
            }
        #pragma unroll
        for (int mi = 0; mi < 2; ++mi) {
            float mx = s[mi][0][0];
            #pragma unroll
            for (int nj = 0; nj < 4; ++nj)
                #pragma unroll
                for (int c = 0; c < 4; ++c) mx = fmaxf(mx, s[mi][nj][c]);
            mx = fmaxf(mx, __shfl_xor(mx, 16));
            mx = fmaxf(mx, __shfl_xor(mx, 32));
            float ssum = 0.f;
            if (__all(mx - mrow[mi] <= 8.f)) {
                float mn = mrow[mi];
                #pragma unroll
                for (int nj = 0; nj < 4; ++nj)
                    #pragma unroll
                    for (int c = 0; c < 4; ++c) {
                        float p = exp2f(s[mi][nj][c] - mn);
                        s[mi][nj][c] = p;
                        ssum += p;
                    }
                ssum += __shfl_xor(ssum, 16);
                ssum += __shfl_xor(ssum, 32);
                lrow[mi] += ssum;
            } else {
                float mn = fmaxf(mrow[mi], mx);
                float scn = exp2f(mrow[mi] - mn);
                mrow[mi] = mn;
                #pragma unroll
                for (int nj = 0; nj < 4; ++nj)
                    #pragma unroll
                    for (int c = 0; c < 4; ++c) {
                        float p = exp2f(s[mi][nj][c] - mn);
                        s[mi][nj][c] = p;
                        ssum += p;
                    }
                ssum += __shfl_xor(ssum, 16);
                ssum += __shfl_xor(ssum, 32);
                lrow[mi] = lrow[mi] * scn + ssum;
                f32x4 scd;
                #pragma unroll
                for (int r = 0; r < 4; ++r) scd[r] = __shfl(scn, 4 * lg + r);
                O[mi][0] *= scd;
                O[mi][1] *= scd;
            }
            #pragma unroll
            for (int nj = 0; nj < 4; ++nj)
                *(uint2*)(Pl[w] + (mi * 16 + l15) * PLD + nj * 16 + 4 * lg) =
                    pk4(s[mi][nj][0], s[mi][nj][1], s[mi][nj][2], s[mi][nj][3]);
        }
        #pragma unroll
        for (int kk = 0; kk < 2; ++kk) {
            bf16x8 vf[2];
            #pragma unroll
            for (int dj = 0; dj < 2; ++dj) {
                int d = dj * 16 + l15;
                int cb = (kc * 128 + kk * 64 + lg * 16) ^ ((l15 & 7) << 4);
                vf[dj] = *(const bf16x8*)((const char*)Vt + d * 512 + cb);
            }
            __builtin_amdgcn_s_setprio(1);
            #pragma unroll
            for (int mi = 0; mi < 2; ++mi) {
                bf16x8 af = *(const bf16x8*)(Pl[w] + (mi * 16 + l15) * PLD + kk * 32 + lg * 8);
                O[mi][0] = __builtin_amdgcn_mfma_f32_16x16x32_bf16(af, vf[0], O[mi][0], 0, 0, 0);
                O[mi][1] = __builtin_amdgcn_mfma_f32_16x16x32_bf16(af, vf[1], O[mi][1], 0, 0, 0);
            }
            __builtin_amdgcn_s_setprio(0);
        }
    }

    #pragma unroll
    for (int mi = 0; mi < 2; ++mi) {
        float linv = 1.f / lrow[mi];
        f32x4 invd;
        #pragma unroll
        for (int r = 0; r < 4; ++r) invd[r] = __shfl(linv, 4 * lg + r);
        #pragma unroll
        for (int dj = 0; dj < 2; ++dj) {
            int d = dj * 16 + l15;
            if (d >= HDz) continue;
            #pragma unroll
            for (int r = 0; r < 4; ++r) {
                int q = qb * 128 + w * 32 + mi * 16 + 4 * lg + r;
                if (q < Sz)
                    o[((size_t)b * Sp + q) * Kp + h * HDz + d] = f2b(O[mi][dj][r] * invd[r]);
            }
        }
    }
}

// ---------------- pool + fc_norm -> bf16 pooled ----------------
__global__ void pool_norm_k(const float* __restrict__ tok, const float* __restrict__ sc,
                            const float* __restrict__ bi, short* __restrict__ pooled) {
    int b = blockIdx.x;
    int t = threadIdx.x;
    float val = 0.f;
    if (t < Dz) {
        const float* base = tok + ((size_t)b * Sp + 1) * Dz + t;
        float s = 0.f;
        for (int si = 0; si < Nz; ++si) s += base[(size_t)si * Dz];
        val = s * (1.f / Nz);
    }
    __shared__ float red[8];
    float sum = val, sq = val * val;
    #pragma unroll
    for (int off = 32; off; off >>= 1) { sum += __shfl_xor(sum, off); sq += __shfl_xor(sq, off); }
    int wave = t >> 6, lane = t & 63;
    if (lane == 0) { red[wave] = sum; red[4 + wave] = sq; }
    __syncthreads();
    sum = red[0] + red[1] + red[2] + red[3];
    sq = red[4] + red[5] + red[6] + red[7];
    float mean = sum * (1.f / Dz);
    float var = sq * (1.f / Dz) - mean * mean;
    float rstd = rsqrtf(var + 1e-6f);
    if (t < Dz) pooled[(size_t)b * Kp + t] = f2b((val - mean) * rstd * sc[t] + bi[t]);
    else if (t < Kp) pooled[(size_t)b * Kp + t] = 0;
}

extern "C" void kernel_launch(void* const* d_in, const int* in_sizes, int n_in,
                              void* d_out, int out_size, void* d_ws, size_t ws_size,
                              hipStream_t stream) {
    const float* x        = (const float*)d_in[0];
    const float* conv_w   = (const float*)d_in[1];
    const float* conv_b   = (const float*)d_in[2];
    const float* cls_tok  = (const float*)d_in[3];
    const float* pos_emb  = (const float*)d_in[4];
    const float* ln1_s    = (const float*)d_in[5];
    const float* ln1_b    = (const float*)d_in[6];
    const float* qkv_w    = (const float*)d_in[7];
    const float* q_bias   = (const float*)d_in[8];
    const float* v_bias   = (const float*)d_in[9];
    const float* rpb      = (const float*)d_in[10];
    const float* proj_w   = (const float*)d_in[11];
    const float* proj_b   = (const float*)d_in[12];
    const float* ln2_s    = (const float*)d_in[13];
    const float* ln2_b    = (const float*)d_in[14];
    const float* fc1_w    = (const float*)d_in[15];
    const float* fc1_b    = (const float*)d_in[16];
    const float* fc2_w    = (const float*)d_in[17];
    const float* fc2_b    = (const float*)d_in[18];
    const float* fcn_s    = (const float*)d_in[19];
    const float* fcn_b    = (const float*)d_in[20];
    const float* head_w   = (const float*)d_in[21];
    const float* head_b   = (const float*)d_in[22];
    float* out = (float*)d_out;

    char* ws = (char*)d_ws;
    float* tok  = (float*)ws;  ws += (size_t)Mp * Dz * 4;        // 13.11 MB
    short* xa   = (short*)ws;  ws += (size_t)Mp * Kp * 2;        // ln1(0) out / qkv0 in
    short* xb   = (short*)ws;  ws += (size_t)Mp * Kp * 2;        // attn out
    short* Qb   = (short*)ws;  ws += (size_t)640 * 8192 * 2;
    short* Kb   = (short*)ws;  ws += (size_t)640 * 8192 * 2;
    short* Vtb  = (short*)ws;  ws += (size_t)640 * 8192 * 2;
    short* wq = (short*)ws;    ws += (size_t)Lz * 640 * Kp * 2;
    short* wp = (short*)ws;    ws += (size_t)Lz * 256 * Kp * 2;
    short* w1 = (short*)ws;    ws += (size_t)Lz * 896 * Kp * 2;
    short* w2 = (short*)ws;    ws += (size_t)Lz * 256 * FFz * 2;
    short* wh = (short*)ws;    ws += (size_t)1024 * Kp * 2;
    short* biasC = (short*)ws; ws += (size_t)Lz * BIASL * 2;
    short* xpb  = (short*)ws;  ws += (size_t)PEM * 64 * 2;
    short* wpe  = (short*)ws;  ws += (size_t)256 * 64 * 2;
    short* pooledb = (short*)ws; ws += (size_t)128 * Kp * 2;

    hipMemsetAsync(xa, 0, (size_t)Mp * Kp * 2 * 2, stream);      // xa, xb
    hipMemsetAsync(Qb, 0, (size_t)640 * 8192 * 2 * 3, stream);
    hipMemsetAsync(pooledb, 0, (size_t)128 * Kp * 2, stream);

    {
        int n;
        n = Lz * 640 * Kp;  cvt_pad_k<<<(n + 255) / 256, 256, 0, stream>>>(qkv_w, wq, 600, 200, 640, Kp, n);
        n = Lz * 256 * Kp;  cvt_pad_k<<<(n + 255) / 256, 256, 0, stream>>>(proj_w, wp, 200, 200, 256, Kp, n);
        n = Lz * 896 * Kp;  cvt_pad_k<<<(n + 255) / 256, 256, 0, stream>>>(fc1_w, w1, 800, 200, 896, Kp, n);
        n = Lz * 256 * FFz; cvt_pad_k<<<(n + 255) / 256, 256, 0, stream>>>(fc2_w, w2, 200, 800, 256, FFz, n);
        n = 1024 * Kp;      cvt_pad_k<<<(n + 255) / 256, 256, 0, stream>>>(head_w, wh, 1000, 200, 1024, Kp, n);
        n = 256 * 64;       cvt_pad_k<<<(n + 255) / 256, 256, 0, stream>>>(conv_w, wpe, 200, 50, 256, 64, n);
    }
    bias_pre4_k<<<dim3(640, Lz), 256, 0, stream>>>(rpb, biasC);

    xcvt_k<<<(PEM * 64) / 256, 256, 0, stream>>>(x, xpb);
    gemm6_k<4, 64, 128><<<4 * (PEM / 128), 256, 0, stream>>>(
        xpb, wpe, conv_b, nullptr, pos_emb, tok,
        nullptr, nullptr, nullptr, PEM, Dz, 64, 64, Dz, 4, PEM / 128);
    cls_k<<<Bz, 256, 0, stream>>>(cls_tok, pos_emb, tok);

    dim3 blk(256);
    ln_k<<<Mp / 4, blk, 0, stream>>>(tok, xa, ln1_s, ln1_b);
    gemm6_k<1, 128, 128><<<5 * (Mp / 128), blk, 0, stream>>>(
        xa, wq, q_bias, v_bias, nullptr, nullptr, Qb, Kb, Vtb,
        Mp, 600, Kp, Kp, 0, 5, Mp / 128);

    for (int l = 0; l < Lz; ++l) {
        attn5_k<<<1280, blk, 0, stream>>>(Qb, Kb, Vtb, biasC + (size_t)l * BIASL, xb);
        int ln = (l + 1) % Lz;
        mlp_fused_k<<<Mp / 16, blk, 0, stream>>>(
            xb, tok,
            wp + (size_t)l * 256 * Kp, proj_b + l * Dz,
            ln2_s + l * Dz, ln2_b + l * Dz,
            w1 + (size_t)l * 896 * Kp, fc1_b + l * FFz,
            w2 + (size_t)l * 256 * FFz, fc2_b + l * Dz,
            ln1_s + (size_t)ln * Dz, ln1_b + (size_t)ln * Dz,
            wq + (size_t)ln * 640 * Kp, q_bias + (size_t)ln * Dz, v_bias + (size_t)ln * Dz,
            Qb, Kb, Vtb, (l + 1 < Lz) ? 1 : 0);
    }

    pool_norm_k<<<Bz, blk, 0, stream>>>(tok, fcn_s, fcn_b, pooledb);
    gemm6_k<0, 128, 128><<<8, blk, 0, stream>>>(
        pooledb, wh, head_b, nullptr, nullptr, out,
        nullptr, nullptr, nullptr, Bz, NCz, Kp, Kp, NCz, 8, 1);
}

// Round 15
// 1366.462 us; speedup vs baseline: 1.5696x; 1.5696x over previous
//
#include <hip/hip_runtime.h>
#include <math.h>

#define Bz 64
#define Tz 12000
#define Pz 50
#define Dz 200
#define Lz 12
#define Hz 10
#define HDz 20
#define FFz 800
#define Nz 240
#define Sz 241
#define Sp 256                // padded seq stride
#define NRDz 482
#define NCz 1000
#define BS (Bz * Sz)          // 15424 valid rows
#define Mp (Bz * Sp)          // 16384 padded rows
#define Kp 224                // K=200 padded to 7*32
#define PEM (Bz * Nz)         // 15360 patch rows
#define SCALEq 0.22360679774997896f
#define LOG2E 1.4426950408889634f
#define SCALE2f (SCALEq * LOG2E)
#define BIASL 655360          // shorts per layer of bias table

typedef __attribute__((ext_vector_type(8))) short bf16x8;
typedef __attribute__((ext_vector_type(4))) float f32x4;

static __device__ __forceinline__ short f2b(float f) {
    unsigned u = __float_as_uint(f);
    unsigned r = (u + 0x7fffu + ((u >> 16) & 1u)) >> 16;
    return (short)r;
}
static __device__ __forceinline__ float b2f(short v) {
    return __uint_as_float(((unsigned)(unsigned short)v) << 16);
}
static __device__ __forceinline__ uint2 pk4(float a, float b, float c, float d) {
    uint2 r;
    asm("v_cvt_pk_bf16_f32 %0, %1, %2" : "=v"(r.x) : "v"(a), "v"(b));
    asm("v_cvt_pk_bf16_f32 %0, %1, %2" : "=v"(r.y) : "v"(c), "v"(d));
    return r;
}
static __device__ __forceinline__ float frcp(float x) {
    float r;
    asm("v_rcp_f32 %0, %1" : "=v"(r) : "v"(x));
    return r;
}
static __device__ __forceinline__ float gelu_f(float v) {
    float u = v * (0.7978845608f + 0.03567740814f * v * v);
    float e = exp2f(2.885390082f * u);
    return v * e * frcp(e + 1.f);
}
static __device__ __forceinline__ void gll16(const void* g, void* l) {
    __builtin_amdgcn_global_load_lds((const __attribute__((address_space(1))) unsigned*)g,
                                     (__attribute__((address_space(3))) unsigned*)l, 16, 0, 0);
}
template <int N> static __device__ __forceinline__ void wait_vm() {
    if constexpr (N == 0) asm volatile("s_waitcnt vmcnt(0)" ::: "memory");
    else if constexpr (N == 1) asm volatile("s_waitcnt vmcnt(1)" ::: "memory");
    else if constexpr (N == 2) asm volatile("s_waitcnt vmcnt(2)" ::: "memory");
    else if constexpr (N == 3) asm volatile("s_waitcnt vmcnt(3)" ::: "memory");
    else if constexpr (N == 4) asm volatile("s_waitcnt vmcnt(4)" ::: "memory");
    else if constexpr (N == 5) asm volatile("s_waitcnt vmcnt(5)" ::: "memory");
    else if constexpr (N == 6) asm volatile("s_waitcnt vmcnt(6)" ::: "memory");
}

// ---------------- f32 [L][N][K] -> bf16 [L][Npad][Kpad] zero-padded ----------------
__global__ void cvt_pad_k(const float* __restrict__ in, short* __restrict__ out,
                          int N, int K, int Npad, int Kpad, int total) {
    int i = blockIdx.x * 256 + threadIdx.x;
    if (i >= total) return;
    int pk = Npad * Kpad;
    int l = i / pk;
    int r = i - l * pk;
    int n = r / Kpad;
    int k = r - n * Kpad;
    float v = (n < N && k < K) ? in[((size_t)l * N + n) * K + k] : 0.f;
    out[i] = f2b(v);
}

// ---------------- x -> bf16 patches [15360][64] ----------------
__global__ void xcvt_k(const float* __restrict__ x, short* __restrict__ xb) {
    int i = blockIdx.x * 256 + threadIdx.x;
    int m = i >> 6, k = i & 63;
    int b = m / Nz, j = m - b * Nz;
    xb[i] = (k < Pz) ? f2b(x[(size_t)b * Tz + j * Pz + k]) : 0;
}

// ---------------- cls rows ----------------
__global__ void cls_k(const float* __restrict__ cls, const float* __restrict__ pos,
                      float* __restrict__ tok) {
    int b = blockIdx.x, d = threadIdx.x;
    if (d < Dz) tok[(size_t)b * Sp * Dz + d] = cls[d] + pos[d];
}

// ---------------- layernorm: f32 (padded rows, ld 200) -> bf16 (ld 224) ----------------
__global__ void ln_k(const float* __restrict__ in, short* __restrict__ out,
                     const float* __restrict__ sc, const float* __restrict__ bi) {
    int wave = threadIdx.x >> 6, lane = threadIdx.x & 63;
    int row = blockIdx.x * 4 + wave;
    if ((row & 255) >= Sz) return;
    const float* x = in + (size_t)row * Dz;
    float v[4];
    float sum = 0.f;
    #pragma unroll
    for (int i = 0; i < 4; ++i) {
        int d = lane + 64 * i;
        v[i] = (d < Dz) ? x[d] : 0.f;
        sum += v[i];
    }
    #pragma unroll
    for (int off = 32; off; off >>= 1) sum += __shfl_xor(sum, off);
    float mean = sum * (1.f / Dz);
    float var = 0.f;
    #pragma unroll
    for (int i = 0; i < 4; ++i) {
        int d = lane + 64 * i;
        if (d < Dz) { float t = v[i] - mean; var += t * t; }
    }
    #pragma unroll
    for (int off = 32; off; off >>= 1) var += __shfl_xor(var, off);
    var *= (1.f / Dz);
    float rstd = rsqrtf(var + 1e-6f);
    short* o = out + (size_t)row * Kp;
    #pragma unroll
    for (int i = 0; i < 4; ++i) {
        int d = lane + 64 * i;
        if (d < Dz) o[d] = f2b((v[i] - mean) * rstd * sc[d] + bi[d]);
        else if (d < Kp) o[d] = 0;
    }
}

// ---------------- bias precompute (ALL layers), swapped-fragment order ----------------
__global__ void bias_pre4_k(const float* __restrict__ tabs, short* __restrict__ bp) {
    int l = blockIdx.y;
    int tid = blockIdx.x * 256 + threadIdx.x;
    const float* tab = tabs + (size_t)l * NRDz * Hz;
    int lane = tid & 63;
    int mi = (tid >> 6) & 1;
    int w  = (tid >> 7) & 3;
    int qb = (tid >> 9) & 1;
    int nj = (tid >> 10) & 3;
    int kc = (tid >> 12) & 3;
    int h  = tid >> 14;
    int q  = qb * 128 + w * 32 + mi * 16 + (lane & 15);
    int k0 = kc * 64 + nj * 16 + 4 * (lane >> 4);
    short4 o;
    #pragma unroll
    for (int r = 0; r < 4; ++r) {
        int k = k0 + r;
        float v;
        if (q > Nz || k > Nz) v = -1e30f;
        else if (k == 0)      v = (q == 0) ? tab[481 * Hz + h] : tab[480 * Hz + h];
        else if (q == 0)      v = tab[479 * Hz + h];
        else                  v = tab[(q - k + 239) * Hz + h];
        ((short*)&o)[r] = f2b(v * LOG2E);
    }
    *(short4*)(bp + (size_t)l * BIASL + (size_t)tid * 4) = o;
}

// ---------------- MFMA GEMM v7: 3-stage counted-vmcnt + XCD swizzle + coalesced epi ----
// MODE 0: f32 +bias (head)   MODE 1: qkv -> Qb/Kb/Vtb   MODE 2: f32 +bias+res (LDS epi)
// MODE 3: bf16 gelu(+bias) (LDS epi)   MODE 4: patch embed
template <int MODE, int BN2, int BM2>
__global__ __launch_bounds__(256) void gemm7_k(
        const short* __restrict__ A, const short* __restrict__ W,
        const float* __restrict__ bias, const float* __restrict__ bias2,
        const float* __restrict__ res, void* __restrict__ outv,
        short* __restrict__ qo, short* __restrict__ ko, short* __restrict__ vo,
        int M, int Nreal, int K, int strideA, int ldo, int gridx, int gridy) {
    constexpr int NJ = BN2 / 32;
    constexpr int MI = BM2 / 32;
    constexpr int AISS = BM2 / 64;
    constexpr int BISS = BN2 / 64;
    constexpr int LPS = AISS + BISS;
    __shared__ short smem[3 * (BM2 + BN2) * 32];
    short* Asb = smem;
    short* Bsb = smem + 3 * BM2 * 32;
    const int t = threadIdx.x;
    const int lane = t & 63, w = t >> 6;
    const int l15 = lane & 15, lg = lane >> 4;
    const int wm = w & 1, wn = w >> 1;

    int bx, by;
    {
        int wg = blockIdx.x;
        if ((gridy & 7) == 0) {
            int xcd = wg & 7, j = wg >> 3;
            bx = j % gridx;
            by = (j / gridx) * 8 + xcd;
        } else {
            bx = wg % gridx;
            by = wg / gridx;
        }
    }
    const int row0 = by * BM2, col0 = bx * BN2;
    const int xsw = (l15 >> 1) & 3;

    f32x4 acc[MI][NJ];
    #pragma unroll
    for (int mi = 0; mi < MI; ++mi)
        #pragma unroll
        for (int nj = 0; nj < NJ; ++nj) {
            f32x4 z = {0.f, 0.f, 0.f, 0.f};
            acc[mi][nj] = z;
        }

    const int nk = K >> 5;

    auto stage = [&](int buf, int kt) {
        const int k0 = kt * 32;
        #pragma unroll
        for (int i = 0; i < AISS; ++i) {
            int c = (w * AISS + i) * 64 + lane;
            int r = c >> 2, q = c & 3;
            const short* gp = A + (size_t)(row0 + r) * strideA + k0 + ((q ^ ((r >> 1) & 3)) * 8);
            gll16(gp, Asb + buf * BM2 * 32 + (w * AISS + i) * 512);
        }
        #pragma unroll
        for (int i = 0; i < BISS; ++i) {
            int c = (w * BISS + i) * 64 + lane;
            int r = c >> 2, q = c & 3;
            const short* gp = W + (size_t)(col0 + r) * K + k0 + ((q ^ ((r >> 1) & 3)) * 8);
            gll16(gp, Bsb + buf * BN2 * 32 + (w * BISS + i) * 512);
        }
    };

    stage(0, 0);
    if (nk > 1) stage(1, 1);
    for (int kt = 0; kt < nk; ++kt) {
        const int cur = kt % 3;
        if (kt + 1 < nk) wait_vm<LPS>();
        else             wait_vm<0>();
        __builtin_amdgcn_s_barrier();
        if (kt + 2 < nk) stage((kt + 2) % 3, kt + 2);
        bf16x8 bfr[NJ], afr[MI];
        #pragma unroll
        for (int nj = 0; nj < NJ; ++nj)
            bfr[nj] = *(const bf16x8*)(Bsb + cur * BN2 * 32 + (wn * (BN2 / 2) + nj * 16 + l15) * 32 + ((lg ^ xsw) * 8));
        #pragma unroll
        for (int mi = 0; mi < MI; ++mi)
            afr[mi] = *(const bf16x8*)(Asb + cur * BM2 * 32 + (wm * (BM2 / 2) + mi * 16 + l15) * 32 + ((lg ^ xsw) * 8));
        #pragma unroll
        for (int mi = 0; mi < MI; ++mi)
            #pragma unroll
            for (int nj = 0; nj < NJ; ++nj)
                acc[mi][nj] = __builtin_amdgcn_mfma_f32_16x16x32_bf16(afr[mi], bfr[nj], acc[mi][nj], 0, 0, 0);
    }

    if (MODE == 2 || MODE == 3) {
        // coalesced epilogue via LDS round-trip
        __syncthreads();
        if (MODE == 3) {
            constexpr int EW = BN2 + 8;
            short* ep = smem;
            #pragma unroll
            for (int mi = 0; mi < MI; ++mi)
                #pragma unroll
                for (int nj = 0; nj < NJ; ++nj) {
                    int nl = wn * (BN2 / 2) + nj * 16 + l15;
                    int n = col0 + nl;
                    float bv = (n < Nreal) ? bias[n] : 0.f;
                    #pragma unroll
                    for (int r = 0; r < 4; ++r)
                        ep[(wm * (BM2 / 2) + mi * 16 + 4 * lg + r) * EW + nl] =
                            f2b(gelu_f(acc[mi][nj][r] + bv));
                }
            __syncthreads();
            constexpr int TPR = BN2 / 8;
            constexpr int RPP = 256 / TPR;
            int rowp = t / TPR, cch = t % TPR;
            #pragma unroll
            for (int p = 0; p < BM2 / RPP; ++p) {
                int row = p * RPP + rowp;
                int n = col0 + cch * 8;
                if (n + 8 <= Nreal)
                    *(bf16x8*)((short*)outv + (size_t)(row0 + row) * ldo + n) =
                        *(const bf16x8*)(ep + row * EW + cch * 8);
            }
        } else {
            constexpr int EWF = BN2 + 4;
            float* epf = (float*)smem;
            #pragma unroll
            for (int mi = 0; mi < MI; ++mi)
                #pragma unroll
                for (int nj = 0; nj < NJ; ++nj) {
                    int nl = wn * (BN2 / 2) + nj * 16 + l15;
                    int n = col0 + nl;
                    float bv = (n < Nreal) ? bias[n] : 0.f;
                    #pragma unroll
                    for (int r = 0; r < 4; ++r)
                        epf[(wm * (BM2 / 2) + mi * 16 + 4 * lg + r) * EWF + nl] =
                            acc[mi][nj][r] + bv;
                }
            __syncthreads();
            constexpr int TPR = BN2 / 4;
            constexpr int RPP = 256 / TPR;
            int rowp = t / TPR, cch = t % TPR;
            #pragma unroll
            for (int p = 0; p < BM2 / RPP; ++p) {
                int row = p * RPP + rowp;
                int n = col0 + cch * 4;
                if (n + 4 <= Nreal) {
                    size_t off = (size_t)(row0 + row) * ldo + n;
                    f32x4 v = *(const f32x4*)(epf + row * EWF + cch * 4);
                    f32x4 rr = *(const f32x4*)(res + off);
                    *(f32x4*)((float*)outv + off) = v + rr;
                }
            }
        }
        return;
    }

    #pragma unroll
    for (int mi = 0; mi < MI; ++mi) {
        #pragma unroll
        for (int nj = 0; nj < NJ; ++nj) {
            int n = col0 + wn * (BN2 / 2) + nj * 16 + l15;
            if (n >= Nreal) continue;
            if (MODE == 1) {
                int which = n >= 400 ? 2 : (n >= 200 ? 1 : 0);
                int hd = n - which * 200;
                int h = hd / 20, d = hd - h * 20;
                int m0 = row0 + wm * (BM2 / 2) + mi * 16 + 4 * lg;
                int b = m0 >> 8, s0 = m0 & 255;
                size_t base = (size_t)(b * Hz + h) * 8192;
                if (which == 2) {
                    short4 o4;
                    float vb = bias2[hd];
                    #pragma unroll
                    for (int r = 0; r < 4; ++r)
                        ((short*)&o4)[r] = f2b(acc[mi][nj][r] + vb);
                    *(short4*)(vo + base + d * 256 + (s0 ^ ((d & 7) << 3))) = o4;
                } else if (which == 0) {
                    float qb = bias[hd];
                    #pragma unroll
                    for (int r = 0; r < 4; ++r)
                        qo[base + (s0 + r) * 32 + d] = f2b((acc[mi][nj][r] + qb) * SCALE2f);
                } else {
                    #pragma unroll
                    for (int r = 0; r < 4; ++r) {
                        int s = s0 + r;
                        ko[base + s * 32 + (((d >> 3) ^ ((s >> 1) & 3)) * 8) + (d & 7)] = f2b(acc[mi][nj][r]);
                    }
                }
            } else if (MODE == 4) {
                #pragma unroll
                for (int r = 0; r < 4; ++r) {
                    int m = row0 + wm * (BM2 / 2) + mi * 16 + 4 * lg + r;
                    int bb = m / Nz, j = m - bb * Nz;
                    size_t trow = (size_t)bb * Sp + j + 1;
                    ((float*)outv)[trow * ldo + n] =
                        acc[mi][nj][r] + bias[n] + res[(size_t)(j + 1) * Dz + n];
                }
            } else {
                #pragma unroll
                for (int r = 0; r < 4; ++r) {
                    int m = row0 + wm * (BM2 / 2) + mi * 16 + 4 * lg + r;
                    if (m >= M) continue;
                    size_t off = (size_t)m * ldo + n;
                    ((float*)outv)[off] = acc[mi][nj][r] + bias[n];
                }
            }
        }
    }
}

// ---------------- MFMA attention v5 (unchanged) ----------------
#define PLD 72
__global__ __launch_bounds__(256) void attn5_k(const short* __restrict__ Qb,
                                               const short* __restrict__ Kb,
                                               const short* __restrict__ Vtb,
                                               const short* __restrict__ biasC,
                                               short* __restrict__ o) {
    const int blk = blockIdx.x;
    const int qb = blk & 1;
    const int bh = blk >> 1;
    const int b = bh / Hz, h = bh - b * Hz;
    __shared__ short Ks[8192];
    __shared__ short Vt[8192];
    __shared__ short Pl[4][32 * PLD];
    const int t = threadIdx.x;
    const int lane = t & 63, w = t >> 6;
    const int l15 = lane & 15, lg = lane >> 4;

    const short* kbh = Kb + (size_t)bh * 8192;
    const short* vbh = Vtb + (size_t)bh * 8192;
    #pragma unroll
    for (int i = 0; i < 4; ++i) {
        int j = w * 4 + i;
        gll16(kbh + (size_t)(j * 64 + lane) * 8, Ks + j * 512);
        gll16(vbh + (size_t)(j * 64 + lane) * 8, Vt + j * 512);
    }
    bf16x8 qfrag[2];
    const short* qbh = Qb + (size_t)bh * 8192;
    #pragma unroll
    for (int mi = 0; mi < 2; ++mi) {
        int qrow = qb * 128 + w * 32 + mi * 16 + l15;
        qfrag[mi] = *(const bf16x8*)(qbh + qrow * 32 + lg * 8);
    }
    const short* bpp = biasC + 4 * (size_t)(lane + 128 * w + 512 * qb + 16384 * h);
    __syncthreads();

    f32x4 O[2][2];
    float mrow[2] = {-1e30f, -1e30f};
    float lrow[2] = {0.f, 0.f};
    {
        f32x4 z = {0.f, 0.f, 0.f, 0.f};
        O[0][0] = z; O[0][1] = z; O[1][0] = z; O[1][1] = z;
    }
    const int xsw = (l15 >> 1) & 3;

    #pragma unroll 1
    for (int kc = 0; kc < 4; ++kc) {
        bf16x8 kf[4];
        #pragma unroll
        for (int nj = 0; nj < 4; ++nj)
            kf[nj] = *(const bf16x8*)(Ks + (kc * 64 + nj * 16 + l15) * 32 + ((lg ^ xsw) * 8));
        f32x4 s[2][4];
        __builtin_amdgcn_s_setprio(1);
        #pragma unroll
        for (int mi = 0; mi < 2; ++mi)
            #pragma unroll
            for (int nj = 0; nj < 4; ++nj) {
                f32x4 z = {0.f, 0.f, 0.f, 0.f};
                s[mi][nj] = __builtin_amdgcn_mfma_f32_16x16x32_bf16(kf[nj], qfrag[mi], z, 0, 0, 0);
            }
        __builtin_amdgcn_s_setprio(0);
        const short* bkc = bpp + kc * 16384;
        #pragma unroll
        for (int mi = 0; mi < 2; ++mi)
            #pragma unroll
            for (int nj = 0; nj < 4; ++nj) {
                short4 bp4 = *(const short4*)(bkc + nj * 4096 + mi * 256);
                s[mi][nj][0] += b2f(bp4.x);
                s[mi][nj][1] += b2f(bp4.y);
                s[mi][nj][2] += b2f(bp4.z);
                s[mi][nj][3] += b2f(bp4.w);
            }
        #pragma unroll
        for (int mi = 0; mi < 2; ++mi) {
            float mx = s[mi][0][0];
            #pragma unroll
            for (int nj = 0; nj < 4; ++nj)
                #pragma unroll
                for (int c = 0; c < 4; ++c) mx = fmaxf(mx, s[mi][nj][c]);
            mx = fmaxf(mx, __shfl_xor(mx, 16));
            mx = fmaxf(mx, __shfl_xor(mx, 32));
            float ssum = 0.f;
            if (__all(mx - mrow[mi] <= 8.f)) {
                float mn = mrow[mi];
                #pragma unroll
                for (int nj = 0; nj < 4; ++nj)
                    #pragma unroll
                    for (int c = 0; c < 4; ++c) {
                        float p = exp2f(s[mi][nj][c] - mn);
                        s[mi][nj][c] = p;
                        ssum += p;
                    }
                ssum += __shfl_xor(ssum, 16);
                ssum += __shfl_xor(ssum, 32);
                lrow[mi] += ssum;
            } else {
                float mn = fmaxf(mrow[mi], mx);
                float scn = exp2f(mrow[mi] - mn);
                mrow[mi] = mn;
                #pragma unroll
                for (int nj = 0; nj < 4; ++nj)
                    #pragma unroll
                    for (int c = 0; c < 4; ++c) {
                        float p = exp2f(s[mi][nj][c] - mn);
                        s[mi][nj][c] = p;
                        ssum += p;
                    }
                ssum += __shfl_xor(ssum, 16);
                ssum += __shfl_xor(ssum, 32);
                lrow[mi] = lrow[mi] * scn + ssum;
                f32x4 scd;
                #pragma unroll
                for (int r = 0; r < 4; ++r) scd[r] = __shfl(scn, 4 * lg + r);
                O[mi][0] *= scd;
                O[mi][1] *= scd;
            }
            #pragma unroll
            for (int nj = 0; nj < 4; ++nj)
                *(uint2*)(Pl[w] + (mi * 16 + l15) * PLD + nj * 16 + 4 * lg) =
                    pk4(s[mi][nj][0], s[mi][nj][1], s[mi][nj][2], s[mi][nj][3]);
        }
        #pragma unroll
        for (int kk = 0; kk < 2; ++kk) {
            bf16x8 vf[2];
            #pragma unroll
            for (int dj = 0; dj < 2; ++dj) {
                int d = dj * 16 + l15;
                int cb = (kc * 128 + kk * 64 + lg * 16) ^ ((l15 & 7) << 4);
                vf[dj] = *(const bf16x8*)((const char*)Vt + d * 512 + cb);
            }
            __builtin_amdgcn_s_setprio(1);
            #pragma unroll
            for (int mi = 0; mi < 2; ++mi) {
                bf16x8 af = *(const bf16x8*)(Pl[w] + (mi * 16 + l15) * PLD + kk * 32 + lg * 8);
                O[mi][0] = __builtin_amdgcn_mfma_f32_16x16x32_bf16(af, vf[0], O[mi][0], 0, 0, 0);
                O[mi][1] = __builtin_amdgcn_mfma_f32_16x16x32_bf16(af, vf[1], O[mi][1], 0, 0, 0);
            }
            __builtin_amdgcn_s_setprio(0);
        }
    }

    #pragma unroll
    for (int mi = 0; mi < 2; ++mi) {
        float linv = 1.f / lrow[mi];
        f32x4 invd;
        #pragma unroll
        for (int r = 0; r < 4; ++r) invd[r] = __shfl(linv, 4 * lg + r);
        #pragma unroll
        for (int dj = 0; dj < 2; ++dj) {
            int d = dj * 16 + l15;
            if (d >= HDz) continue;
            #pragma unroll
            for (int r = 0; r < 4; ++r) {
                int q = qb * 128 + w * 32 + mi * 16 + 4 * lg + r;
                if (q < Sz)
                    o[((size_t)b * Sp + q) * Kp + h * HDz + d] = f2b(O[mi][dj][r] * invd[r]);
            }
        }
    }
}

// ---------------- pool + fc_norm -> bf16 pooled ----------------
__global__ void pool_norm_k(const float* __restrict__ tok, const float* __restrict__ sc,
                            const float* __restrict__ bi, short* __restrict__ pooled) {
    int b = blockIdx.x;
    int t = threadIdx.x;
    float val = 0.f;
    if (t < Dz) {
        const float* base = tok + ((size_t)b * Sp + 1) * Dz + t;
        float s = 0.f;
        for (int si = 0; si < Nz; ++si) s += base[(size_t)si * Dz];
        val = s * (1.f / Nz);
    }
    __shared__ float red[8];
    float sum = val, sq = val * val;
    #pragma unroll
    for (int off = 32; off; off >>= 1) { sum += __shfl_xor(sum, off); sq += __shfl_xor(sq, off); }
    int wave = t >> 6, lane = t & 63;
    if (lane == 0) { red[wave] = sum; red[4 + wave] = sq; }
    __syncthreads();
    sum = red[0] + red[1] + red[2] + red[3];
    sq = red[4] + red[5] + red[6] + red[7];
    float mean = sum * (1.f / Dz);
    float var = sq * (1.f / Dz) - mean * mean;
    float rstd = rsqrtf(var + 1e-6f);
    if (t < Dz) pooled[(size_t)b * Kp + t] = f2b((val - mean) * rstd * sc[t] + bi[t]);
    else if (t < Kp) pooled[(size_t)b * Kp + t] = 0;
}

extern "C" void kernel_launch(void* const* d_in, const int* in_sizes, int n_in,
                              void* d_out, int out_size, void* d_ws, size_t ws_size,
                              hipStream_t stream) {
    const float* x        = (const float*)d_in[0];
    const float* conv_w   = (const float*)d_in[1];
    const float* conv_b   = (const float*)d_in[2];
    const float* cls_tok  = (const float*)d_in[3];
    const float* pos_emb  = (const float*)d_in[4];
    const float* ln1_s    = (const float*)d_in[5];
    const float* ln1_b    = (const float*)d_in[6];
    const float* qkv_w    = (const float*)d_in[7];
    const float* q_bias   = (const float*)d_in[8];
    const float* v_bias   = (const float*)d_in[9];
    const float* rpb      = (const float*)d_in[10];
    const float* proj_w   = (const float*)d_in[11];
    const float* proj_b   = (const float*)d_in[12];
    const float* ln2_s    = (const float*)d_in[13];
    const float* ln2_b    = (const float*)d_in[14];
    const float* fc1_w    = (const float*)d_in[15];
    const float* fc1_b    = (const float*)d_in[16];
    const float* fc2_w    = (const float*)d_in[17];
    const float* fc2_b    = (const float*)d_in[18];
    const float* fcn_s    = (const float*)d_in[19];
    const float* fcn_b    = (const float*)d_in[20];
    const float* head_w   = (const float*)d_in[21];
    const float* head_b   = (const float*)d_in[22];
    float* out = (float*)d_out;

    char* ws = (char*)d_ws;
    float* tok  = (float*)ws;  ws += (size_t)Mp * Dz * 4;
    short* xa   = (short*)ws;  ws += (size_t)Mp * Kp * 2;
    short* xb   = (short*)ws;  ws += (size_t)Mp * Kp * 2;
    short* xc   = (short*)ws;  ws += (size_t)Mp * Kp * 2;
    short* mid  = (short*)ws;  ws += (size_t)Mp * FFz * 2;
    short* Qb   = (short*)ws;  ws += (size_t)640 * 8192 * 2;
    short* Kb   = (short*)ws;  ws += (size_t)640 * 8192 * 2;
    short* Vtb  = (short*)ws;  ws += (size_t)640 * 8192 * 2;
    short* wq = (short*)ws;    ws += (size_t)Lz * 640 * Kp * 2;
    short* wp = (short*)ws;    ws += (size_t)Lz * 256 * Kp * 2;
    short* w1 = (short*)ws;    ws += (size_t)Lz * 896 * Kp * 2;
    short* w2 = (short*)ws;    ws += (size_t)Lz * 256 * FFz * 2;
    short* wh = (short*)ws;    ws += (size_t)1024 * Kp * 2;
    short* biasC = (short*)ws; ws += (size_t)Lz * BIASL * 2;
    short* xpb  = (short*)ws;  ws += (size_t)PEM * 64 * 2;
    short* wpe  = (short*)ws;  ws += (size_t)256 * 64 * 2;
    short* pooledb = (short*)ws; ws += (size_t)128 * Kp * 2;

    hipMemsetAsync(xa, 0, (size_t)Mp * Kp * 2 * 3, stream);
    hipMemsetAsync(Qb, 0, (size_t)640 * 8192 * 2 * 3, stream);
    hipMemsetAsync(pooledb, 0, (size_t)128 * Kp * 2, stream);

    {
        int n;
        n = Lz * 640 * Kp;  cvt_pad_k<<<(n + 255) / 256, 256, 0, stream>>>(qkv_w, wq, 600, 200, 640, Kp, n);
        n = Lz * 256 * Kp;  cvt_pad_k<<<(n + 255) / 256, 256, 0, stream>>>(proj_w, wp, 200, 200, 256, Kp, n);
        n = Lz * 896 * Kp;  cvt_pad_k<<<(n + 255) / 256, 256, 0, stream>>>(fc1_w, w1, 800, 200, 896, Kp, n);
        n = Lz * 256 * FFz; cvt_pad_k<<<(n + 255) / 256, 256, 0, stream>>>(fc2_w, w2, 200, 800, 256, FFz, n);
        n = 1024 * Kp;      cvt_pad_k<<<(n + 255) / 256, 256, 0, stream>>>(head_w, wh, 1000, 200, 1024, Kp, n);
        n = 256 * 64;       cvt_pad_k<<<(n + 255) / 256, 256, 0, stream>>>(conv_w, wpe, 200, 50, 256, 64, n);
    }
    bias_pre4_k<<<dim3(640, Lz), 256, 0, stream>>>(rpb, biasC);

    xcvt_k<<<(PEM * 64) / 256, 256, 0, stream>>>(x, xpb);
    gemm7_k<4, 64, 128><<<4 * (PEM / 128), 256, 0, stream>>>(
        xpb, wpe, conv_b, nullptr, pos_emb, tok,
        nullptr, nullptr, nullptr, PEM, Dz, 64, 64, Dz, 4, PEM / 128);
    cls_k<<<Bz, 256, 0, stream>>>(cls_tok, pos_emb, tok);

    dim3 blk(256);
    ln_k<<<Mp / 4, blk, 0, stream>>>(tok, xa, ln1_s, ln1_b);
    for (int l = 0; l < Lz; ++l) {
        gemm7_k<1, 128, 128><<<5 * (Mp / 128), blk, 0, stream>>>(
            xa, wq + (size_t)l * 640 * Kp, q_bias + l * Dz, v_bias + l * Dz,
            nullptr, nullptr, Qb, Kb, Vtb,
            Mp, 600, Kp, Kp, 0, 5, Mp / 128);
        attn5_k<<<1280, blk, 0, stream>>>(Qb, Kb, Vtb, biasC + (size_t)l * BIASL, xb);
        gemm7_k<2, 64, 64><<<4 * (Mp / 64), blk, 0, stream>>>(
            xb, wp + (size_t)l * 256 * Kp, proj_b + l * Dz, nullptr,
            tok, tok, nullptr, nullptr, nullptr,
            Mp, Dz, Kp, Kp, Dz, 4, Mp / 64);
        ln_k<<<Mp / 4, blk, 0, stream>>>(tok, xc, ln2_s + l * Dz, ln2_b + l * Dz);
        gemm7_k<3, 128, 128><<<7 * (Mp / 128), blk, 0, stream>>>(
            xc, w1 + (size_t)l * 896 * Kp, fc1_b + l * FFz, nullptr,
            nullptr, mid, nullptr, nullptr, nullptr,
            Mp, FFz, Kp, Kp, FFz, 7, Mp / 128);
        gemm7_k<2, 64, 64><<<4 * (Mp / 64), blk, 0, stream>>>(
            mid, w2 + (size_t)l * 256 * FFz, fc2_b + l * Dz, nullptr,
            tok, tok, nullptr, nullptr, nullptr,
            Mp, Dz, FFz, FFz, Dz, 4, Mp / 64);
        ln_k<<<Mp / 4, blk, 0, stream>>>(tok, xa, ln1_s + (size_t)((l + 1) % Lz) * Dz,
                                         ln1_b + (size_t)((l + 1) % Lz) * Dz);
    }

    pool_norm_k<<<Bz, blk, 0, stream>>>(tok, fcn_s, fcn_b, pooledb);
    gemm7_k<0, 128, 128><<<8, blk, 0, stream>>>(
        pooledb, wh, head_b, nullptr, nullptr, out,
        nullptr, nullptr, nullptr, Bz, NCz, Kp, Kp, NCz, 8, 1);
}

// Round 16
// 1363.754 us; speedup vs baseline: 1.5727x; 1.0020x over previous
//
#include <hip/hip_runtime.h>
#include <math.h>

#define Bz 64
#define Tz 12000
#define Pz 50
#define Dz 200
#define Lz 12
#define Hz 10
#define HDz 20
#define FFz 800
#define Nz 240
#define Sz 241
#define Sp 256                // padded seq stride
#define NRDz 482
#define NCz 1000
#define BS (Bz * Sz)          // 15424 valid rows
#define Mp (Bz * Sp)          // 16384 padded rows
#define Kp 224                // K=200 padded to 7*32
#define PEM (Bz * Nz)         // 15360 patch rows
#define SCALEq 0.22360679774997896f
#define LOG2E 1.4426950408889634f
#define SCALE2f (SCALEq * LOG2E)
#define BIASL 655360          // shorts per layer of bias table

typedef __attribute__((ext_vector_type(8))) short bf16x8;
typedef __attribute__((ext_vector_type(4))) float f32x4;

static __device__ __forceinline__ short f2b(float f) {
    unsigned u = __float_as_uint(f);
    unsigned r = (u + 0x7fffu + ((u >> 16) & 1u)) >> 16;
    return (short)r;
}
static __device__ __forceinline__ float b2f(short v) {
    return __uint_as_float(((unsigned)(unsigned short)v) << 16);
}
static __device__ __forceinline__ uint2 pk4(float a, float b, float c, float d) {
    uint2 r;
    asm("v_cvt_pk_bf16_f32 %0, %1, %2" : "=v"(r.x) : "v"(a), "v"(b));
    asm("v_cvt_pk_bf16_f32 %0, %1, %2" : "=v"(r.y) : "v"(c), "v"(d));
    return r;
}
static __device__ __forceinline__ float frcp(float x) {
    float r;
    asm("v_rcp_f32 %0, %1" : "=v"(r) : "v"(x));
    return r;
}
static __device__ __forceinline__ float gelu_f(float v) {
    float u = v * (0.7978845608f + 0.03567740814f * v * v);
    float e = exp2f(2.885390082f * u);
    return v * e * frcp(e + 1.f);
}
static __device__ __forceinline__ void gll16(const void* g, void* l) {
    __builtin_amdgcn_global_load_lds((const __attribute__((address_space(1))) unsigned*)g,
                                     (__attribute__((address_space(3))) unsigned*)l, 16, 0, 0);
}
template <int N> static __device__ __forceinline__ void wait_vm() {
    if constexpr (N == 0) asm volatile("s_waitcnt vmcnt(0)" ::: "memory");
    else if constexpr (N == 1) asm volatile("s_waitcnt vmcnt(1)" ::: "memory");
    else if constexpr (N == 2) asm volatile("s_waitcnt vmcnt(2)" ::: "memory");
    else if constexpr (N == 3) asm volatile("s_waitcnt vmcnt(3)" ::: "memory");
    else if constexpr (N == 4) asm volatile("s_waitcnt vmcnt(4)" ::: "memory");
    else if constexpr (N == 5) asm volatile("s_waitcnt vmcnt(5)" ::: "memory");
    else if constexpr (N == 6) asm volatile("s_waitcnt vmcnt(6)" ::: "memory");
}

// ---------------- f32 [L][N][K] -> bf16 [L][Npad][Kpad] zero-padded ----------------
__global__ void cvt_pad_k(const float* __restrict__ in, short* __restrict__ out,
                          int N, int K, int Npad, int Kpad, int total) {
    int i = blockIdx.x * 256 + threadIdx.x;
    if (i >= total) return;
    int pk = Npad * Kpad;
    int l = i / pk;
    int r = i - l * pk;
    int n = r / Kpad;
    int k = r - n * Kpad;
    float v = (n < N && k < K) ? in[((size_t)l * N + n) * K + k] : 0.f;
    out[i] = f2b(v);
}

// ---------------- x -> bf16 patches [15360][64] ----------------
__global__ void xcvt_k(const float* __restrict__ x, short* __restrict__ xb) {
    int i = blockIdx.x * 256 + threadIdx.x;
    int m = i >> 6, k = i & 63;
    int b = m / Nz, j = m - b * Nz;
    xb[i] = (k < Pz) ? f2b(x[(size_t)b * Tz + j * Pz + k]) : 0;
}

// ---------------- cls rows ----------------
__global__ void cls_k(const float* __restrict__ cls, const float* __restrict__ pos,
                      float* __restrict__ tok) {
    int b = blockIdx.x, d = threadIdx.x;
    if (d < Dz) tok[(size_t)b * Sp * Dz + d] = cls[d] + pos[d];
}

// ---------------- layernorm: f32 (padded rows, ld 200) -> bf16 (ld 224) ----------------
__global__ void ln_k(const float* __restrict__ in, short* __restrict__ out,
                     const float* __restrict__ sc, const float* __restrict__ bi) {
    int wave = threadIdx.x >> 6, lane = threadIdx.x & 63;
    int row = blockIdx.x * 4 + wave;
    if ((row & 255) >= Sz) return;
    const float* x = in + (size_t)row * Dz;
    float v[4];
    float sum = 0.f;
    #pragma unroll
    for (int i = 0; i < 4; ++i) {
        int d = lane + 64 * i;
        v[i] = (d < Dz) ? x[d] : 0.f;
        sum += v[i];
    }
    #pragma unroll
    for (int off = 32; off; off >>= 1) sum += __shfl_xor(sum, off);
    float mean = sum * (1.f / Dz);
    float var = 0.f;
    #pragma unroll
    for (int i = 0; i < 4; ++i) {
        int d = lane + 64 * i;
        if (d < Dz) { float t = v[i] - mean; var += t * t; }
    }
    #pragma unroll
    for (int off = 32; off; off >>= 1) var += __shfl_xor(var, off);
    var *= (1.f / Dz);
    float rstd = rsqrtf(var + 1e-6f);
    short* o = out + (size_t)row * Kp;
    #pragma unroll
    for (int i = 0; i < 4; ++i) {
        int d = lane + 64 * i;
        if (d < Dz) o[d] = f2b((v[i] - mean) * rstd * sc[d] + bi[d]);
        else if (d < Kp) o[d] = 0;
    }
}

// ---------------- bias precompute (ALL layers), swapped-fragment order ----------------
__global__ void bias_pre4_k(const float* __restrict__ tabs, short* __restrict__ bp) {
    int l = blockIdx.y;
    int tid = blockIdx.x * 256 + threadIdx.x;
    const float* tab = tabs + (size_t)l * NRDz * Hz;
    int lane = tid & 63;
    int mi = (tid >> 6) & 1;
    int w  = (tid >> 7) & 3;
    int qb = (tid >> 9) & 1;
    int nj = (tid >> 10) & 3;
    int kc = (tid >> 12) & 3;
    int h  = tid >> 14;
    int q  = qb * 128 + w * 32 + mi * 16 + (lane & 15);
    int k0 = kc * 64 + nj * 16 + 4 * (lane >> 4);
    short4 o;
    #pragma unroll
    for (int r = 0; r < 4; ++r) {
        int k = k0 + r;
        float v;
        if (q > Nz || k > Nz) v = -1e30f;
        else if (k == 0)      v = (q == 0) ? tab[481 * Hz + h] : tab[480 * Hz + h];
        else if (q == 0)      v = tab[479 * Hz + h];
        else                  v = tab[(q - k + 239) * Hz + h];
        ((short*)&o)[r] = f2b(v * LOG2E);
    }
    *(short4*)(bp + (size_t)l * BIASL + (size_t)tid * 4) = o;
}

// ---------------- MFMA GEMM v8: 3-stage counted-vmcnt + XCD swizzle + coalesced epi ----
// MODE 0: f32 +bias (head)   MODE 1: qkv -> Qb/Kb/Vtb (SWAPPED operands, wide stores)
// MODE 2: f32 +bias+res (LDS epi)   MODE 3: bf16 gelu(+bias) (LDS epi)   MODE 4: patch embed
template <int MODE, int BN2, int BM2>
__global__ __launch_bounds__(256) void gemm8_k(
        const short* __restrict__ A, const short* __restrict__ W,
        const float* __restrict__ bias, const float* __restrict__ bias2,
        const float* __restrict__ res, void* __restrict__ outv,
        short* __restrict__ qo, short* __restrict__ ko, short* __restrict__ vo,
        int M, int Nreal, int K, int strideA, int ldo, int gridx, int gridy) {
    constexpr int NJ = BN2 / 32;
    constexpr int MI = BM2 / 32;
    constexpr int AISS = BM2 / 64;
    constexpr int BISS = BN2 / 64;
    constexpr int LPS = AISS + BISS;
    __shared__ short smem[3 * (BM2 + BN2) * 32];
    short* Asb = smem;
    short* Bsb = smem + 3 * BM2 * 32;
    const int t = threadIdx.x;
    const int lane = t & 63, w = t >> 6;
    const int l15 = lane & 15, lg = lane >> 4;
    const int wm = w & 1, wn = w >> 1;

    int bx, by;
    {
        int wg = blockIdx.x;
        if ((gridy & 7) == 0) {
            int xcd = wg & 7, j = wg >> 3;
            bx = j % gridx;
            by = (j / gridx) * 8 + xcd;
        } else {
            bx = wg % gridx;
            by = wg / gridx;
        }
    }
    const int row0 = by * BM2, col0 = bx * BN2;
    const int xsw = (l15 >> 1) & 3;

    f32x4 acc[MI][NJ];
    #pragma unroll
    for (int mi = 0; mi < MI; ++mi)
        #pragma unroll
        for (int nj = 0; nj < NJ; ++nj) {
            f32x4 z = {0.f, 0.f, 0.f, 0.f};
            acc[mi][nj] = z;
        }

    const int nk = K >> 5;

    auto stage = [&](int buf, int kt) {
        const int k0 = kt * 32;
        #pragma unroll
        for (int i = 0; i < AISS; ++i) {
            int c = (w * AISS + i) * 64 + lane;
            int r = c >> 2, q = c & 3;
            const short* gp = A + (size_t)(row0 + r) * strideA + k0 + ((q ^ ((r >> 1) & 3)) * 8);
            gll16(gp, Asb + buf * BM2 * 32 + (w * AISS + i) * 512);
        }
        #pragma unroll
        for (int i = 0; i < BISS; ++i) {
            int c = (w * BISS + i) * 64 + lane;
            int r = c >> 2, q = c & 3;
            const short* gp = W + (size_t)(col0 + r) * K + k0 + ((q ^ ((r >> 1) & 3)) * 8);
            gll16(gp, Bsb + buf * BN2 * 32 + (w * BISS + i) * 512);
        }
    };

    stage(0, 0);
    if (nk > 1) stage(1, 1);
    for (int kt = 0; kt < nk; ++kt) {
        const int cur = kt % 3;
        if (kt + 1 < nk) wait_vm<LPS>();
        else             wait_vm<0>();
        __builtin_amdgcn_s_barrier();
        if (kt + 2 < nk) stage((kt + 2) % 3, kt + 2);
        bf16x8 bfr[NJ], afr[MI];
        #pragma unroll
        for (int nj = 0; nj < NJ; ++nj)
            bfr[nj] = *(const bf16x8*)(Bsb + cur * BN2 * 32 + (wn * (BN2 / 2) + nj * 16 + l15) * 32 + ((lg ^ xsw) * 8));
        #pragma unroll
        for (int mi = 0; mi < MI; ++mi)
            afr[mi] = *(const bf16x8*)(Asb + cur * BM2 * 32 + (wm * (BM2 / 2) + mi * 16 + l15) * 32 + ((lg ^ xsw) * 8));
        #pragma unroll
        for (int mi = 0; mi < MI; ++mi)
            #pragma unroll
            for (int nj = 0; nj < NJ; ++nj) {
                if (MODE == 1)
                    acc[mi][nj] = __builtin_amdgcn_mfma_f32_16x16x32_bf16(bfr[nj], afr[mi], acc[mi][nj], 0, 0, 0);
                else
                    acc[mi][nj] = __builtin_amdgcn_mfma_f32_16x16x32_bf16(afr[mi], bfr[nj], acc[mi][nj], 0, 0, 0);
            }
    }

    if (MODE == 1) {
        // swapped-C: D row = n (4 consecutive: 4*lg+r), D col = m (l15). 200%4==0 =>
        // each 4-run stays within one (which, head) segment.
        #pragma unroll
        for (int mi = 0; mi < MI; ++mi) {
            int m = row0 + wm * (BM2 / 2) + mi * 16 + l15;
            int b = m >> 8, s = m & 255;
            #pragma unroll
            for (int nj = 0; nj < NJ; ++nj) {
                int n0 = col0 + wn * (BN2 / 2) + nj * 16 + 4 * lg;
                if (n0 >= 600) continue;
                int which = n0 >= 400 ? 2 : (n0 >= 200 ? 1 : 0);
                int hd = n0 - which * 200;
                int h = hd / 20, d0 = hd - h * 20;
                size_t base = (size_t)(b * Hz + h) * 8192;
                if (which == 0) {
                    f32x4 qb4 = *(const f32x4*)(bias + hd);
                    short4 o4;
                    #pragma unroll
                    for (int r = 0; r < 4; ++r)
                        ((short*)&o4)[r] = f2b((acc[mi][nj][r] + qb4[r]) * SCALE2f);
                    *(short4*)(qo + base + s * 32 + d0) = o4;
                } else if (which == 1) {
                    int oct = (d0 >> 3) ^ ((s >> 1) & 3);
                    short4 o4;
                    #pragma unroll
                    for (int r = 0; r < 4; ++r)
                        ((short*)&o4)[r] = f2b(acc[mi][nj][r]);
                    *(short4*)(ko + base + s * 32 + oct * 8 + (d0 & 7)) = o4;
                } else {
                    f32x4 vb4 = *(const f32x4*)(bias2 + hd);
                    #pragma unroll
                    for (int r = 0; r < 4; ++r) {
                        int d = d0 + r;
                        vo[base + d * 256 + (s ^ ((d & 7) << 3))] = f2b(acc[mi][nj][r] + vb4[r]);
                    }
                }
            }
        }
        return;
    }

    if (MODE == 2 || MODE == 3) {
        __syncthreads();
        if (MODE == 3) {
            constexpr int EW = BN2 + 8;
            short* ep = smem;
            #pragma unroll
            for (int mi = 0; mi < MI; ++mi)
                #pragma unroll
                for (int nj = 0; nj < NJ; ++nj) {
                    int nl = wn * (BN2 / 2) + nj * 16 + l15;
                    int n = col0 + nl;
                    float bv = (n < Nreal) ? bias[n] : 0.f;
                    #pragma unroll
                    for (int r = 0; r < 4; ++r)
                        ep[(wm * (BM2 / 2) + mi * 16 + 4 * lg + r) * EW + nl] =
                            f2b(gelu_f(acc[mi][nj][r] + bv));
                }
            __syncthreads();
            constexpr int TPR = BN2 / 8;
            constexpr int RPP = 256 / TPR;
            int rowp = t / TPR, cch = t % TPR;
            #pragma unroll
            for (int p = 0; p < BM2 / RPP; ++p) {
                int row = p * RPP + rowp;
                int n = col0 + cch * 8;
                if (n + 8 <= Nreal)
                    *(bf16x8*)((short*)outv + (size_t)(row0 + row) * ldo + n) =
                        *(const bf16x8*)(ep + row * EW + cch * 8);
            }
        } else {
            constexpr int EWF = BN2 + 4;
            float* epf = (float*)smem;
            #pragma unroll
            for (int mi = 0; mi < MI; ++mi)
                #pragma unroll
                for (int nj = 0; nj < NJ; ++nj) {
                    int nl = wn * (BN2 / 2) + nj * 16 + l15;
                    int n = col0 + nl;
                    float bv = (n < Nreal) ? bias[n] : 0.f;
                    #pragma unroll
                    for (int r = 0; r < 4; ++r)
                        epf[(wm * (BM2 / 2) + mi * 16 + 4 * lg + r) * EWF + nl] =
                            acc[mi][nj][r] + bv;
                }
            __syncthreads();
            constexpr int TPR = BN2 / 4;
            constexpr int RPP = 256 / TPR;
            int rowp = t / TPR, cch = t % TPR;
            #pragma unroll
            for (int p = 0; p < BM2 / RPP; ++p) {
                int row = p * RPP + rowp;
                int n = col0 + cch * 4;
                if (n + 4 <= Nreal) {
                    size_t off = (size_t)(row0 + row) * ldo + n;
                    f32x4 v = *(const f32x4*)(epf + row * EWF + cch * 4);
                    f32x4 rr = *(const f32x4*)(res + off);
                    *(f32x4*)((float*)outv + off) = v + rr;
                }
            }
        }
        return;
    }

    #pragma unroll
    for (int mi = 0; mi < MI; ++mi) {
        #pragma unroll
        for (int nj = 0; nj < NJ; ++nj) {
            int n = col0 + wn * (BN2 / 2) + nj * 16 + l15;
            if (n >= Nreal) continue;
            if (MODE == 4) {
                #pragma unroll
                for (int r = 0; r < 4; ++r) {
                    int m = row0 + wm * (BM2 / 2) + mi * 16 + 4 * lg + r;
                    int bb = m / Nz, j = m - bb * Nz;
                    size_t trow = (size_t)bb * Sp + j + 1;
                    ((float*)outv)[trow * ldo + n] =
                        acc[mi][nj][r] + bias[n] + res[(size_t)(j + 1) * Dz + n];
                }
            } else {
                #pragma unroll
                for (int r = 0; r < 4; ++r) {
                    int m = row0 + wm * (BM2 / 2) + mi * 16 + 4 * lg + r;
                    if (m >= M) continue;
                    size_t off = (size_t)m * ldo + n;
                    ((float*)outv)[off] = acc[mi][nj][r] + bias[n];
                }
            }
        }
    }
}

// ---------------- MFMA attention v5 (unchanged) ----------------
#define PLD 72
__global__ __launch_bounds__(256) void attn5_k(const short* __restrict__ Qb,
                                               const short* __restrict__ Kb,
                                               const short* __restrict__ Vtb,
                                               const short* __restrict__ biasC,
                                               short* __restrict__ o) {
    const int blk = blockIdx.x;
    const int qb = blk & 1;
    const int bh = blk >> 1;
    const int b = bh / Hz, h = bh - b * Hz;
    __shared__ short Ks[8192];
    __shared__ short Vt[8192];
    __shared__ short Pl[4][32 * PLD];
    const int t = threadIdx.x;
    const int lane = t & 63, w = t >> 6;
    const int l15 = lane & 15, lg = lane >> 4;

    const short* kbh = Kb + (size_t)bh * 8192;
    const short* vbh = Vtb + (size_t)bh * 8192;
    #pragma unroll
    for (int i = 0; i < 4; ++i) {
        int j = w * 4 + i;
        gll16(kbh + (size_t)(j * 64 + lane) * 8, Ks + j * 512);
        gll16(vbh + (size_t)(j * 64 + lane) * 8, Vt + j * 512);
    }
    bf16x8 qfrag[2];
    const short* qbh = Qb + (size_t)bh * 8192;
    #pragma unroll
    for (int mi = 0; mi < 2; ++mi) {
        int qrow = qb * 128 + w * 32 + mi * 16 + l15;
        qfrag[mi] = *(const bf16x8*)(qbh + qrow * 32 + lg * 8);
    }
    const short* bpp = biasC + 4 * (size_t)(lane + 128 * w + 512 * qb + 16384 * h);
    __syncthreads();

    f32x4 O[2][2];
    float mrow[2] = {-1e30f, -1e30f};
    float lrow[2] = {0.f, 0.f};
    {
        f32x4 z = {0.f, 0.f, 0.f, 0.f};
        O[0][0] = z; O[0][1] = z; O[1][0] = z; O[1][1] = z;
    }
    const int xsw = (l15 >> 1) & 3;

    #pragma unroll 1
    for (int kc = 0; kc < 4; ++kc) {
        bf16x8 kf[4];
        #pragma unroll
        for (int nj = 0; nj < 4; ++nj)
            kf[nj] = *(const bf16x8*)(Ks + (kc * 64 + nj * 16 + l15) * 32 + ((lg ^ xsw) * 8));
        f32x4 s[2][4];
        __builtin_amdgcn_s_setprio(1);
        #pragma unroll
        for (int mi = 0; mi < 2; ++mi)
            #pragma unroll
            for (int nj = 0; nj < 4; ++nj) {
                f32x4 z = {0.f, 0.f, 0.f, 0.f};
                s[mi][nj] = __builtin_amdgcn_mfma_f32_16x16x32_bf16(kf[nj], qfrag[mi], z, 0, 0, 0);
            }
        __builtin_amdgcn_s_setprio(0);
        const short* bkc = bpp + kc * 16384;
        #pragma unroll
        for (int mi = 0; mi < 2; ++mi)
            #pragma unroll
            for (int nj = 0; nj < 4; ++nj) {
                short4 bp4 = *(const short4*)(bkc + nj * 4096 + mi * 256);
                s[mi][nj][0] += b2f(bp4.x);
                s[mi][nj][1] += b2f(bp4.y);
                s[mi][nj][2] += b2f(bp4.z);
                s[mi][nj][3] += b2f(bp4.w);
            }
        #pragma unroll
        for (int mi = 0; mi < 2; ++mi) {
            float mx = s[mi][0][0];
            #pragma unroll
            for (int nj = 0; nj < 4; ++nj)
                #pragma unroll
                for (int c = 0; c < 4; ++c) mx = fmaxf(mx, s[mi][nj][c]);
            mx = fmaxf(mx, __shfl_xor(mx, 16));
            mx = fmaxf(mx, __shfl_xor(mx, 32));
            float ssum = 0.f;
            if (__all(mx - mrow[mi] <= 8.f)) {
                float mn = mrow[mi];
                #pragma unroll
                for (int nj = 0; nj < 4; ++nj)
                    #pragma unroll
                    for (int c = 0; c < 4; ++c) {
                        float p = exp2f(s[mi][nj][c] - mn);
                        s[mi][nj][c] = p;
                        ssum += p;
                    }
                ssum += __shfl_xor(ssum, 16);
                ssum += __shfl_xor(ssum, 32);
                lrow[mi] += ssum;
            } else {
                float mn = fmaxf(mrow[mi], mx);
                float scn = exp2f(mrow[mi] - mn);
                mrow[mi] = mn;
                #pragma unroll
                for (int nj = 0; nj < 4; ++nj)
                    #pragma unroll
                    for (int c = 0; c < 4; ++c) {
                        float p = exp2f(s[mi][nj][c] - mn);
                        s[mi][nj][c] = p;
                        ssum += p;
                    }
                ssum += __shfl_xor(ssum, 16);
                ssum += __shfl_xor(ssum, 32);
                lrow[mi] = lrow[mi] * scn + ssum;
                f32x4 scd;
                #pragma unroll
                for (int r = 0; r < 4; ++r) scd[r] = __shfl(scn, 4 * lg + r);
                O[mi][0] *= scd;
                O[mi][1] *= scd;
            }
            #pragma unroll
            for (int nj = 0; nj < 4; ++nj)
                *(uint2*)(Pl[w] + (mi * 16 + l15) * PLD + nj * 16 + 4 * lg) =
                    pk4(s[mi][nj][0], s[mi][nj][1], s[mi][nj][2], s[mi][nj][3]);
        }
        #pragma unroll
        for (int kk = 0; kk < 2; ++kk) {
            bf16x8 vf[2];
            #pragma unroll
            for (int dj = 0; dj < 2; ++dj) {
                int d = dj * 16 + l15;
                int cb = (kc * 128 + kk * 64 + lg * 16) ^ ((l15 & 7) << 4);
                vf[dj] = *(const bf16x8*)((const char*)Vt + d * 512 + cb);
            }
            __builtin_amdgcn_s_setprio(1);
            #pragma unroll
            for (int mi = 0; mi < 2; ++mi) {
                bf16x8 af = *(const bf16x8*)(Pl[w] + (mi * 16 + l15) * PLD + kk * 32 + lg * 8);
                O[mi][0] = __builtin_amdgcn_mfma_f32_16x16x32_bf16(af, vf[0], O[mi][0], 0, 0, 0);
                O[mi][1] = __builtin_amdgcn_mfma_f32_16x16x32_bf16(af, vf[1], O[mi][1], 0, 0, 0);
            }
            __builtin_amdgcn_s_setprio(0);
        }
    }

    #pragma unroll
    for (int mi = 0; mi < 2; ++mi) {
        float linv = 1.f / lrow[mi];
        f32x4 invd;
        #pragma unroll
        for (int r = 0; r < 4; ++r) invd[r] = __shfl(linv, 4 * lg + r);
        #pragma unroll
        for (int dj = 0; dj < 2; ++dj) {
            int d = dj * 16 + l15;
            if (d >= HDz) continue;
            #pragma unroll
            for (int r = 0; r < 4; ++r) {
                int q = qb * 128 + w * 32 + mi * 16 + 4 * lg + r;
                if (q < Sz)
                    o[((size_t)b * Sp + q) * Kp + h * HDz + d] = f2b(O[mi][dj][r] * invd[r]);
            }
        }
    }
}

// ---------------- pool + fc_norm -> bf16 pooled ----------------
__global__ void pool_norm_k(const float* __restrict__ tok, const float* __restrict__ sc,
                            const float* __restrict__ bi, short* __restrict__ pooled) {
    int b = blockIdx.x;
    int t = threadIdx.x;
    float val = 0.f;
    if (t < Dz) {
        const float* base = tok + ((size_t)b * Sp + 1) * Dz + t;
        float s = 0.f;
        for (int si = 0; si < Nz; ++si) s += base[(size_t)si * Dz];
        val = s * (1.f / Nz);
    }
    __shared__ float red[8];
    float sum = val, sq = val * val;
    #pragma unroll
    for (int off = 32; off; off >>= 1) { sum += __shfl_xor(sum, off); sq += __shfl_xor(sq, off); }
    int wave = t >> 6, lane = t & 63;
    if (lane == 0) { red[wave] = sum; red[4 + wave] = sq; }
    __syncthreads();
    sum = red[0] + red[1] + red[2] + red[3];
    sq = red[4] + red[5] + red[6] + red[7];
    float mean = sum * (1.f / Dz);
    float var = sq * (1.f / Dz) - mean * mean;
    float rstd = rsqrtf(var + 1e-6f);
    if (t < Dz) pooled[(size_t)b * Kp + t] = f2b((val - mean) * rstd * sc[t] + bi[t]);
    else if (t < Kp) pooled[(size_t)b * Kp + t] = 0;
}

extern "C" void kernel_launch(void* const* d_in, const int* in_sizes, int n_in,
                              void* d_out, int out_size, void* d_ws, size_t ws_size,
                              hipStream_t stream) {
    const float* x        = (const float*)d_in[0];
    const float* conv_w   = (const float*)d_in[1];
    const float* conv_b   = (const float*)d_in[2];
    const float* cls_tok  = (const float*)d_in[3];
    const float* pos_emb  = (const float*)d_in[4];
    const float* ln1_s    = (const float*)d_in[5];
    const float* ln1_b    = (const float*)d_in[6];
    const float* qkv_w    = (const float*)d_in[7];
    const float* q_bias   = (const float*)d_in[8];
    const float* v_bias   = (const float*)d_in[9];
    const float* rpb      = (const float*)d_in[10];
    const float* proj_w   = (const float*)d_in[11];
    const float* proj_b   = (const float*)d_in[12];
    const float* ln2_s    = (const float*)d_in[13];
    const float* ln2_b    = (const float*)d_in[14];
    const float* fc1_w    = (const float*)d_in[15];
    const float* fc1_b    = (const float*)d_in[16];
    const float* fc2_w    = (const float*)d_in[17];
    const float* fc2_b    = (const float*)d_in[18];
    const float* fcn_s    = (const float*)d_in[19];
    const float* fcn_b    = (const float*)d_in[20];
    const float* head_w   = (const float*)d_in[21];
    const float* head_b   = (const float*)d_in[22];
    float* out = (float*)d_out;

    char* ws = (char*)d_ws;
    float* tok  = (float*)ws;  ws += (size_t)Mp * Dz * 4;
    short* xa   = (short*)ws;  ws += (size_t)Mp * Kp * 2;
    short* xb   = (short*)ws;  ws += (size_t)Mp * Kp * 2;
    short* xc   = (short*)ws;  ws += (size_t)Mp * Kp * 2;
    short* mid  = (short*)ws;  ws += (size_t)Mp * FFz * 2;
    short* Qb   = (short*)ws;  ws += (size_t)640 * 8192 * 2;
    short* Kb   = (short*)ws;  ws += (size_t)640 * 8192 * 2;
    short* Vtb  = (short*)ws;  ws += (size_t)640 * 8192 * 2;
    short* wq = (short*)ws;    ws += (size_t)Lz * 640 * Kp * 2;
    short* wp = (short*)ws;    ws += (size_t)Lz * 256 * Kp * 2;
    short* w1 = (short*)ws;    ws += (size_t)Lz * 896 * Kp * 2;
    short* w2 = (short*)ws;    ws += (size_t)Lz * 256 * FFz * 2;
    short* wh = (short*)ws;    ws += (size_t)1024 * Kp * 2;
    short* biasC = (short*)ws; ws += (size_t)Lz * BIASL * 2;
    short* xpb  = (short*)ws;  ws += (size_t)PEM * 64 * 2;
    short* wpe  = (short*)ws;  ws += (size_t)256 * 64 * 2;
    short* pooledb = (short*)ws; ws += (size_t)128 * Kp * 2;

    // xa pad rows feed K/V values -> must be finite (NaN there would poison softmax).
    // Other buffers' garbage only reaches pad/discarded outputs (MFMA rows independent).
    hipMemsetAsync(xa, 0, (size_t)Mp * Kp * 2, stream);
    hipMemsetAsync(pooledb, 0, (size_t)128 * Kp * 2, stream);

    {
        int n;
        n = Lz * 640 * Kp;  cvt_pad_k<<<(n + 255) / 256, 256, 0, stream>>>(qkv_w, wq, 600, 200, 640, Kp, n);
        n = Lz * 256 * Kp;  cvt_pad_k<<<(n + 255) / 256, 256, 0, stream>>>(proj_w, wp, 200, 200, 256, Kp, n);
        n = Lz * 896 * Kp;  cvt_pad_k<<<(n + 255) / 256, 256, 0, stream>>>(fc1_w, w1, 800, 200, 896, Kp, n);
        n = Lz * 256 * FFz; cvt_pad_k<<<(n + 255) / 256, 256, 0, stream>>>(fc2_w, w2, 200, 800, 256, FFz, n);
        n = 1024 * Kp;      cvt_pad_k<<<(n + 255) / 256, 256, 0, stream>>>(head_w, wh, 1000, 200, 1024, Kp, n);
        n = 256 * 64;       cvt_pad_k<<<(n + 255) / 256, 256, 0, stream>>>(conv_w, wpe, 200, 50, 256, 64, n);
    }
    bias_pre4_k<<<dim3(640, Lz), 256, 0, stream>>>(rpb, biasC);

    xcvt_k<<<(PEM * 64) / 256, 256, 0, stream>>>(x, xpb);
    gemm8_k<4, 64, 128><<<4 * (PEM / 128), 256, 0, stream>>>(
        xpb, wpe, conv_b, nullptr, pos_emb, tok,
        nullptr, nullptr, nullptr, PEM, Dz, 64, 64, Dz, 4, PEM / 128);
    cls_k<<<Bz, 256, 0, stream>>>(cls_tok, pos_emb, tok);

    dim3 blk(256);
    ln_k<<<Mp / 4, blk, 0, stream>>>(tok, xa, ln1_s, ln1_b);
    for (int l = 0; l < Lz; ++l) {
        gemm8_k<1, 128, 128><<<5 * (Mp / 128), blk, 0, stream>>>(
            xa, wq + (size_t)l * 640 * Kp, q_bias + l * Dz, v_bias + l * Dz,
            nullptr, nullptr, Qb, Kb, Vtb,
            Mp, 600, Kp, Kp, 0, 5, Mp / 128);
        attn5_k<<<1280, blk, 0, stream>>>(Qb, Kb, Vtb, biasC + (size_t)l * BIASL, xb);
        gemm8_k<2, 64, 64><<<4 * (Mp / 64), blk, 0, stream>>>(
            xb, wp + (size_t)l * 256 * Kp, proj_b + l * Dz, nullptr,
            tok, tok, nullptr, nullptr, nullptr,
            Mp, Dz, Kp, Kp, Dz, 4, Mp / 64);
        ln_k<<<Mp / 4, blk, 0, stream>>>(tok, xc, ln2_s + l * Dz, ln2_b + l * Dz);
        gemm8_k<3, 128, 128><<<7 * (Mp / 128), blk, 0, stream>>>(
            xc, w1 + (size_t)l * 896 * Kp, fc1_b + l * FFz, nullptr,
            nullptr, mid, nullptr, nullptr, nullptr,
            Mp, FFz, Kp, Kp, FFz, 7, Mp / 128);
        gemm8_k<2, 64, 64><<<4 * (Mp / 64), blk, 0, stream>>>(
            mid, w2 + (size_t)l * 256 * FFz, fc2_b + l * Dz, nullptr,
            tok, tok, nullptr, nullptr, nullptr,
            Mp, Dz, FFz, FFz, Dz, 4, Mp / 64);
        ln_k<<<Mp / 4, blk, 0, stream>>>(tok, xa, ln1_s + (size_t)((l + 1) % Lz) * Dz,
                                         ln1_b + (size_t)((l + 1) % Lz) * Dz);
    }

    pool_norm_k<<<Bz, blk, 0, stream>>>(tok, fcn_s, fcn_b, pooledb);
    gemm8_k<0, 128, 128><<<8, blk, 0, stream>>>(
        pooledb, wh, head_b, nullptr, nullptr, out,
        nullptr, nullptr, nullptr, Bz, NCz, Kp, Kp, NCz, 8, 1);
}

// Round 17
// 1355.113 us; speedup vs baseline: 1.5828x; 1.0064x over previous
//
#include <hip/hip_runtime.h>
#include <math.h>

#define Bz 64
#define Tz 12000
#define Pz 50
#define Dz 200
#define Lz 12
#define Hz 10
#define HDz 20
#define FFz 800
#define Nz 240
#define Sz 241
#define Sp 256                // padded seq stride
#define NRDz 482
#define NCz 1000
#define BS (Bz * Sz)          // 15424 valid rows
#define Mp (Bz * Sp)          // 16384 padded rows
#define Kp 224                // K=200 padded to 7*32
#define PEM (Bz * Nz)         // 15360 patch rows
#define SCALEq 0.22360679774997896f
#define LOG2E 1.4426950408889634f
#define SCALE2f (SCALEq * LOG2E)
#define BIASL 655360          // shorts per layer of bias table

typedef __attribute__((ext_vector_type(8))) short bf16x8;
typedef __attribute__((ext_vector_type(4))) float f32x4;

static __device__ __forceinline__ short f2b(float f) {
    unsigned u = __float_as_uint(f);
    unsigned r = (u + 0x7fffu + ((u >> 16) & 1u)) >> 16;
    return (short)r;
}
static __device__ __forceinline__ float b2f(short v) {
    return __uint_as_float(((unsigned)(unsigned short)v) << 16);
}
static __device__ __forceinline__ uint2 pk4(float a, float b, float c, float d) {
    uint2 r;
    asm("v_cvt_pk_bf16_f32 %0, %1, %2" : "=v"(r.x) : "v"(a), "v"(b));
    asm("v_cvt_pk_bf16_f32 %0, %1, %2" : "=v"(r.y) : "v"(c), "v"(d));
    return r;
}
static __device__ __forceinline__ float frcp(float x) {
    float r;
    asm("v_rcp_f32 %0, %1" : "=v"(r) : "v"(x));
    return r;
}
static __device__ __forceinline__ float gelu_f(float v) {
    float u = v * (0.7978845608f + 0.03567740814f * v * v);
    float e = exp2f(2.885390082f * u);
    return v * e * frcp(e + 1.f);
}
static __device__ __forceinline__ void gll16(const void* g, void* l) {
    __builtin_amdgcn_global_load_lds((const __attribute__((address_space(1))) unsigned*)g,
                                     (__attribute__((address_space(3))) unsigned*)l, 16, 0, 0);
}
template <int N> static __device__ __forceinline__ void wait_vm() {
    if constexpr (N == 0) asm volatile("s_waitcnt vmcnt(0)" ::: "memory");
    else if constexpr (N == 1) asm volatile("s_waitcnt vmcnt(1)" ::: "memory");
    else if constexpr (N == 2) asm volatile("s_waitcnt vmcnt(2)" ::: "memory");
    else if constexpr (N == 3) asm volatile("s_waitcnt vmcnt(3)" ::: "memory");
    else if constexpr (N == 4) asm volatile("s_waitcnt vmcnt(4)" ::: "memory");
    else if constexpr (N == 5) asm volatile("s_waitcnt vmcnt(5)" ::: "memory");
    else if constexpr (N == 6) asm volatile("s_waitcnt vmcnt(6)" ::: "memory");
}

// ---------------- f32 [L][N][K] -> bf16 [L][Npad][Kpad] zero-padded ----------------
__global__ void cvt_pad_k(const float* __restrict__ in, short* __restrict__ out,
                          int N, int K, int Npad, int Kpad, int total) {
    int i = blockIdx.x * 256 + threadIdx.x;
    if (i >= total) return;
    int pk = Npad * Kpad;
    int l = i / pk;
    int r = i - l * pk;
    int n = r / Kpad;
    int k = r - n * Kpad;
    float v = (n < N && k < K) ? in[((size_t)l * N + n) * K + k] : 0.f;
    out[i] = f2b(v);
}

// ---------------- x -> bf16 patches [15360][64] ----------------
__global__ void xcvt_k(const float* __restrict__ x, short* __restrict__ xb) {
    int i = blockIdx.x * 256 + threadIdx.x;
    int m = i >> 6, k = i & 63;
    int b = m / Nz, j = m - b * Nz;
    xb[i] = (k < Pz) ? f2b(x[(size_t)b * Tz + j * Pz + k]) : 0;
}

// ---------------- cls rows ----------------
__global__ void cls_k(const float* __restrict__ cls, const float* __restrict__ pos,
                      float* __restrict__ tok) {
    int b = blockIdx.x, d = threadIdx.x;
    if (d < Dz) tok[(size_t)b * Sp * Dz + d] = cls[d] + pos[d];
}

// ---------------- layernorm: f32 (padded rows, ld 200) -> bf16 (ld 224) ----------------
__global__ void ln_k(const float* __restrict__ in, short* __restrict__ out,
                     const float* __restrict__ sc, const float* __restrict__ bi) {
    int wave = threadIdx.x >> 6, lane = threadIdx.x & 63;
    int row = blockIdx.x * 4 + wave;
    if ((row & 255) >= Sz) return;
    const float* x = in + (size_t)row * Dz;
    float v[4];
    float sum = 0.f;
    #pragma unroll
    for (int i = 0; i < 4; ++i) {
        int d = lane + 64 * i;
        v[i] = (d < Dz) ? x[d] : 0.f;
        sum += v[i];
    }
    #pragma unroll
    for (int off = 32; off; off >>= 1) sum += __shfl_xor(sum, off);
    float mean = sum * (1.f / Dz);
    float var = 0.f;
    #pragma unroll
    for (int i = 0; i < 4; ++i) {
        int d = lane + 64 * i;
        if (d < Dz) { float t = v[i] - mean; var += t * t; }
    }
    #pragma unroll
    for (int off = 32; off; off >>= 1) var += __shfl_xor(var, off);
    var *= (1.f / Dz);
    float rstd = rsqrtf(var + 1e-6f);
    short* o = out + (size_t)row * Kp;
    #pragma unroll
    for (int i = 0; i < 4; ++i) {
        int d = lane + 64 * i;
        if (d < Dz) o[d] = f2b((v[i] - mean) * rstd * sc[d] + bi[d]);
        else if (d < Kp) o[d] = 0;
    }
}

// ---------------- bias precompute (ALL layers), swapped-fragment order ----------------
__global__ void bias_pre4_k(const float* __restrict__ tabs, short* __restrict__ bp) {
    int l = blockIdx.y;
    int tid = blockIdx.x * 256 + threadIdx.x;
    const float* tab = tabs + (size_t)l * NRDz * Hz;
    int lane = tid & 63;
    int mi = (tid >> 6) & 1;
    int w  = (tid >> 7) & 3;
    int qb = (tid >> 9) & 1;
    int nj = (tid >> 10) & 3;
    int kc = (tid >> 12) & 3;
    int h  = tid >> 14;
    int q  = qb * 128 + w * 32 + mi * 16 + (lane & 15);
    int k0 = kc * 64 + nj * 16 + 4 * (lane >> 4);
    short4 o;
    #pragma unroll
    for (int r = 0; r < 4; ++r) {
        int k = k0 + r;
        float v;
        if (q > Nz || k > Nz) v = -1e30f;
        else if (k == 0)      v = (q == 0) ? tab[481 * Hz + h] : tab[480 * Hz + h];
        else if (q == 0)      v = tab[479 * Hz + h];
        else                  v = tab[(q - k + 239) * Hz + h];
        ((short*)&o)[r] = f2b(v * LOG2E);
    }
    *(short4*)(bp + (size_t)l * BIASL + (size_t)tid * 4) = o;
}

// ---------------- MFMA GEMM v8: 3-stage counted-vmcnt + XCD swizzle + coalesced epi ----
// MODE 0: f32 +bias (head)   MODE 1: qkv -> Qb/Kb/Vtb (SWAPPED operands, wide stores)
// MODE 2: f32 +bias+res (LDS epi)   MODE 3: bf16 gelu(+bias) (LDS epi)   MODE 4: patch embed
template <int MODE, int BN2, int BM2>
__global__ __launch_bounds__(256) void gemm8_k(
        const short* __restrict__ A, const short* __restrict__ W,
        const float* __restrict__ bias, const float* __restrict__ bias2,
        const float* __restrict__ res, void* __restrict__ outv,
        short* __restrict__ qo, short* __restrict__ ko, short* __restrict__ vo,
        int M, int Nreal, int K, int strideA, int ldo, int gridx, int gridy) {
    constexpr int NJ = BN2 / 32;
    constexpr int MI = BM2 / 32;
    constexpr int AISS = BM2 / 64;
    constexpr int BISS = BN2 / 64;
    constexpr int LPS = AISS + BISS;
    __shared__ short smem[3 * (BM2 + BN2) * 32];
    short* Asb = smem;
    short* Bsb = smem + 3 * BM2 * 32;
    const int t = threadIdx.x;
    const int lane = t & 63, w = t >> 6;
    const int l15 = lane & 15, lg = lane >> 4;
    const int wm = w & 1, wn = w >> 1;

    int bx, by;
    {
        int wg = blockIdx.x;
        if ((gridy & 7) == 0) {
            int xcd = wg & 7, j = wg >> 3;
            bx = j % gridx;
            by = (j / gridx) * 8 + xcd;
        } else {
            bx = wg % gridx;
            by = wg / gridx;
        }
    }
    const int row0 = by * BM2, col0 = bx * BN2;
    const int xsw = (l15 >> 1) & 3;

    f32x4 acc[MI][NJ];
    #pragma unroll
    for (int mi = 0; mi < MI; ++mi)
        #pragma unroll
        for (int nj = 0; nj < NJ; ++nj) {
            f32x4 z = {0.f, 0.f, 0.f, 0.f};
            acc[mi][nj] = z;
        }

    const int nk = K >> 5;

    auto stage = [&](int buf, int kt) {
        const int k0 = kt * 32;
        #pragma unroll
        for (int i = 0; i < AISS; ++i) {
            int c = (w * AISS + i) * 64 + lane;
            int r = c >> 2, q = c & 3;
            const short* gp = A + (size_t)(row0 + r) * strideA + k0 + ((q ^ ((r >> 1) & 3)) * 8);
            gll16(gp, Asb + buf * BM2 * 32 + (w * AISS + i) * 512);
        }
        #pragma unroll
        for (int i = 0; i < BISS; ++i) {
            int c = (w * BISS + i) * 64 + lane;
            int r = c >> 2, q = c & 3;
            const short* gp = W + (size_t)(col0 + r) * K + k0 + ((q ^ ((r >> 1) & 3)) * 8);
            gll16(gp, Bsb + buf * BN2 * 32 + (w * BISS + i) * 512);
        }
    };

    stage(0, 0);
    if (nk > 1) stage(1, 1);
    for (int kt = 0; kt < nk; ++kt) {
        const int cur = kt % 3;
        if (kt + 1 < nk) wait_vm<LPS>();
        else             wait_vm<0>();
        __builtin_amdgcn_s_barrier();
        if (kt + 2 < nk) stage((kt + 2) % 3, kt + 2);
        bf16x8 bfr[NJ], afr[MI];
        #pragma unroll
        for (int nj = 0; nj < NJ; ++nj)
            bfr[nj] = *(const bf16x8*)(Bsb + cur * BN2 * 32 + (wn * (BN2 / 2) + nj * 16 + l15) * 32 + ((lg ^ xsw) * 8));
        #pragma unroll
        for (int mi = 0; mi < MI; ++mi)
            afr[mi] = *(const bf16x8*)(Asb + cur * BM2 * 32 + (wm * (BM2 / 2) + mi * 16 + l15) * 32 + ((lg ^ xsw) * 8));
        #pragma unroll
        for (int mi = 0; mi < MI; ++mi)
            #pragma unroll
            for (int nj = 0; nj < NJ; ++nj) {
                if (MODE == 1)
                    acc[mi][nj] = __builtin_amdgcn_mfma_f32_16x16x32_bf16(bfr[nj], afr[mi], acc[mi][nj], 0, 0, 0);
                else
                    acc[mi][nj] = __builtin_amdgcn_mfma_f32_16x16x32_bf16(afr[mi], bfr[nj], acc[mi][nj], 0, 0, 0);
            }
    }

    if (MODE == 1) {
        // swapped-C: D row = n (4 consecutive: 4*lg+r), D col = m (l15). 200%4==0 =>
        // each 4-run stays within one (which, head) segment.
        #pragma unroll
        for (int mi = 0; mi < MI; ++mi) {
            int m = row0 + wm * (BM2 / 2) + mi * 16 + l15;
            int b = m >> 8, s = m & 255;
            #pragma unroll
            for (int nj = 0; nj < NJ; ++nj) {
                int n0 = col0 + wn * (BN2 / 2) + nj * 16 + 4 * lg;
                if (n0 >= 600) continue;
                int which = n0 >= 400 ? 2 : (n0 >= 200 ? 1 : 0);
                int hd = n0 - which * 200;
                int h = hd / 20, d0 = hd - h * 20;
                size_t base = (size_t)(b * Hz + h) * 8192;
                if (which == 0) {
                    f32x4 qb4 = *(const f32x4*)(bias + hd);
                    short4 o4;
                    #pragma unroll
                    for (int r = 0; r < 4; ++r)
                        ((short*)&o4)[r] = f2b((acc[mi][nj][r] + qb4[r]) * SCALE2f);
                    *(short4*)(qo + base + s * 32 + d0) = o4;
                } else if (which == 1) {
                    int oct = (d0 >> 3) ^ ((s >> 1) & 3);
                    short4 o4;
                    #pragma unroll
                    for (int r = 0; r < 4; ++r)
                        ((short*)&o4)[r] = f2b(acc[mi][nj][r]);
                    *(short4*)(ko + base + s * 32 + oct * 8 + (d0 & 7)) = o4;
                } else {
                    f32x4 vb4 = *(const f32x4*)(bias2 + hd);
                    #pragma unroll
                    for (int r = 0; r < 4; ++r) {
                        int d = d0 + r;
                        vo[base + d * 256 + (s ^ ((d & 7) << 3))] = f2b(acc[mi][nj][r] + vb4[r]);
                    }
                }
            }
        }
        return;
    }

    if (MODE == 2 || MODE == 3) {
        __syncthreads();
        if (MODE == 3) {
            constexpr int EW = BN2 + 8;
            short* ep = smem;
            #pragma unroll
            for (int mi = 0; mi < MI; ++mi)
                #pragma unroll
                for (int nj = 0; nj < NJ; ++nj) {
                    int nl = wn * (BN2 / 2) + nj * 16 + l15;
                    int n = col0 + nl;
                    float bv = (n < Nreal) ? bias[n] : 0.f;
                    #pragma unroll
                    for (int r = 0; r < 4; ++r)
                        ep[(wm * (BM2 / 2) + mi * 16 + 4 * lg + r) * EW + nl] =
                            f2b(gelu_f(acc[mi][nj][r] + bv));
                }
            __syncthreads();
            constexpr int TPR = BN2 / 8;
            constexpr int RPP = 256 / TPR;
            int rowp = t / TPR, cch = t % TPR;
            #pragma unroll
            for (int p = 0; p < BM2 / RPP; ++p) {
                int row = p * RPP + rowp;
                int n = col0 + cch * 8;
                if (n + 8 <= Nreal)
                    *(bf16x8*)((short*)outv + (size_t)(row0 + row) * ldo + n) =
                        *(const bf16x8*)(ep + row * EW + cch * 8);
            }
        } else {
            constexpr int EWF = BN2 + 4;
            float* epf = (float*)smem;
            #pragma unroll
            for (int mi = 0; mi < MI; ++mi)
                #pragma unroll
                for (int nj = 0; nj < NJ; ++nj) {
                    int nl = wn * (BN2 / 2) + nj * 16 + l15;
                    int n = col0 + nl;
                    float bv = (n < Nreal) ? bias[n] : 0.f;
                    #pragma unroll
                    for (int r = 0; r < 4; ++r)
                        epf[(wm * (BM2 / 2) + mi * 16 + 4 * lg + r) * EWF + nl] =
                            acc[mi][nj][r] + bv;
                }
            __syncthreads();
            constexpr int TPR = BN2 / 4;
            constexpr int RPP = 256 / TPR;
            int rowp = t / TPR, cch = t % TPR;
            #pragma unroll
            for (int p = 0; p < BM2 / RPP; ++p) {
                int row = p * RPP + rowp;
                int n = col0 + cch * 4;
                if (n + 4 <= Nreal) {
                    size_t off = (size_t)(row0 + row) * ldo + n;
                    f32x4 v = *(const f32x4*)(epf + row * EWF + cch * 4);
                    f32x4 rr = *(const f32x4*)(res + off);
                    *(f32x4*)((float*)outv + off) = v + rr;
                }
            }
        }
        return;
    }

    #pragma unroll
    for (int mi = 0; mi < MI; ++mi) {
        #pragma unroll
        for (int nj = 0; nj < NJ; ++nj) {
            int n = col0 + wn * (BN2 / 2) + nj * 16 + l15;
            if (n >= Nreal) continue;
            if (MODE == 4) {
                #pragma unroll
                for (int r = 0; r < 4; ++r) {
                    int m = row0 + wm * (BM2 / 2) + mi * 16 + 4 * lg + r;
                    int bb = m / Nz, j = m - bb * Nz;
                    size_t trow = (size_t)bb * Sp + j + 1;
                    ((float*)outv)[trow * ldo + n] =
                        acc[mi][nj][r] + bias[n] + res[(size_t)(j + 1) * Dz + n];
                }
            } else {
                #pragma unroll
                for (int r = 0; r < 4; ++r) {
                    int m = row0 + wm * (BM2 / 2) + mi * 16 + 4 * lg + r;
                    if (m >= M) continue;
                    size_t off = (size_t)m * ldo + n;
                    ((float*)outv)[off] = acc[mi][nj][r] + bias[n];
                }
            }
        }
    }
}

// ---------------- MFMA attention v5 (unchanged) ----------------
#define PLD 72
__global__ __launch_bounds__(256) void attn5_k(const short* __restrict__ Qb,
                                               const short* __restrict__ Kb,
                                               const short* __restrict__ Vtb,
                                               const short* __restrict__ biasC,
                                               short* __restrict__ o) {
    const int blk = blockIdx.x;
    const int qb = blk & 1;
    const int bh = blk >> 1;
    const int b = bh / Hz, h = bh - b * Hz;
    __shared__ short Ks[8192];
    __shared__ short Vt[8192];
    __shared__ short Pl[4][32 * PLD];
    const int t = threadIdx.x;
    const int lane = t & 63, w = t >> 6;
    const int l15 = lane & 15, lg = lane >> 4;

    const short* kbh = Kb + (size_t)bh * 8192;
    const short* vbh = Vtb + (size_t)bh * 8192;
    #pragma unroll
    for (int i = 0; i < 4; ++i) {
        int j = w * 4 + i;
        gll16(kbh + (size_t)(j * 64 + lane) * 8, Ks + j * 512);
        gll16(vbh + (size_t)(j * 64 + lane) * 8, Vt + j * 512);
    }
    bf16x8 qfrag[2];
    const short* qbh = Qb + (size_t)bh * 8192;
    #pragma unroll
    for (int mi = 0; mi < 2; ++mi) {
        int qrow = qb * 128 + w * 32 + mi * 16 + l15;
        qfrag[mi] = *(const bf16x8*)(qbh + qrow * 32 + lg * 8);
    }
    const short* bpp = biasC + 4 * (size_t)(lane + 128 * w + 512 * qb + 16384 * h);
    __syncthreads();

    f32x4 O[2][2];
    float mrow[2] = {-1e30f, -1e30f};
    float lrow[2] = {0.f, 0.f};
    {
        f32x4 z = {0.f, 0.f, 0.f, 0.f};
        O[0][0] = z; O[0][1] = z; O[1][0] = z; O[1][1] = z;
    }
    const int xsw = (l15 >> 1) & 3;

    #pragma unroll 1
    for (int kc = 0; kc < 4; ++kc) {
        bf16x8 kf[4];
        #pragma unroll
        for (int nj = 0; nj < 4; ++nj)
            kf[nj] = *(const bf16x8*)(Ks + (kc * 64 + nj * 16 + l15) * 32 + ((lg ^ xsw) * 8));
        f32x4 s[2][4];
        __builtin_amdgcn_s_setprio(1);
        #pragma unroll
        for (int mi = 0; mi < 2; ++mi)
            #pragma unroll
            for (int nj = 0; nj < 4; ++nj) {
                f32x4 z = {0.f, 0.f, 0.f, 0.f};
                s[mi][nj] = __builtin_amdgcn_mfma_f32_16x16x32_bf16(kf[nj], qfrag[mi], z, 0, 0, 0);
            }
        __builtin_amdgcn_s_setprio(0);
        const short* bkc = bpp + kc * 16384;
        #pragma unroll
        for (int mi = 0; mi < 2; ++mi)
            #pragma unroll
            for (int nj = 0; nj < 4; ++nj) {
                short4 bp4 = *(const short4*)(bkc + nj * 4096 + mi * 256);
                s[mi][nj][0] += b2f(bp4.x);
                s[mi][nj][1] += b2f(bp4.y);
                s[mi][nj][2] += b2f(bp4.z);
                s[mi][nj][3] += b2f(bp4.w);
            }
        #pragma unroll
        for (int mi = 0; mi < 2; ++mi) {
            float mx = s[mi][0][0];
            #pragma unroll
            for (int nj = 0; nj < 4; ++nj)
                #pragma unroll
                for (int c = 0; c < 4; ++c) mx = fmaxf(mx, s[mi][nj][c]);
            mx = fmaxf(mx, __shfl_xor(mx, 16));
            mx = fmaxf(mx, __shfl_xor(mx, 32));
            float ssum = 0.f;
            if (__all(mx - mrow[mi] <= 8.f)) {
                float mn = mrow[mi];
                #pragma unroll
                for (int nj = 0; nj < 4; ++nj)
                    #pragma unroll
                    for (int c = 0; c < 4; ++c) {
                        float p = exp2f(s[mi][nj][c] - mn);
                        s[mi][nj][c] = p;
                        ssum += p;
                    }
                ssum += __shfl_xor(ssum, 16);
                ssum += __shfl_xor(ssum, 32);
                lrow[mi] += ssum;
            } else {
                float mn = fmaxf(mrow[mi], mx);
                float scn = exp2f(mrow[mi] - mn);
                mrow[mi] = mn;
                #pragma unroll
                for (int nj = 0; nj < 4; ++nj)
                    #pragma unroll
                    for (int c = 0; c < 4; ++c) {
                        float p = exp2f(s[mi][nj][c] - mn);
                        s[mi][nj][c] = p;
                        ssum += p;
                    }
                ssum += __shfl_xor(ssum, 16);
                ssum += __shfl_xor(ssum, 32);
                lrow[mi] = lrow[mi] * scn + ssum;
                f32x4 scd;
                #pragma unroll
                for (int r = 0; r < 4; ++r) scd[r] = __shfl(scn, 4 * lg + r);
                O[mi][0] *= scd;
                O[mi][1] *= scd;
            }
            #pragma unroll
            for (int nj = 0; nj < 4; ++nj)
                *(uint2*)(Pl[w] + (mi * 16 + l15) * PLD + nj * 16 + 4 * lg) =
                    pk4(s[mi][nj][0], s[mi][nj][1], s[mi][nj][2], s[mi][nj][3]);
        }
        #pragma unroll
        for (int kk = 0; kk < 2; ++kk) {
            bf16x8 vf[2];
            #pragma unroll
            for (int dj = 0; dj < 2; ++dj) {
                int d = dj * 16 + l15;
                int cb = (kc * 128 + kk * 64 + lg * 16) ^ ((l15 & 7) << 4);
                vf[dj] = *(const bf16x8*)((const char*)Vt + d * 512 + cb);
            }
            __builtin_amdgcn_s_setprio(1);
            #pragma unroll
            for (int mi = 0; mi < 2; ++mi) {
                bf16x8 af = *(const bf16x8*)(Pl[w] + (mi * 16 + l15) * PLD + kk * 32 + lg * 8);
                O[mi][0] = __builtin_amdgcn_mfma_f32_16x16x32_bf16(af, vf[0], O[mi][0], 0, 0, 0);
                O[mi][1] = __builtin_amdgcn_mfma_f32_16x16x32_bf16(af, vf[1], O[mi][1], 0, 0, 0);
            }
            __builtin_amdgcn_s_setprio(0);
        }
    }

    #pragma unroll
    for (int mi = 0; mi < 2; ++mi) {
        float linv = 1.f / lrow[mi];
        f32x4 invd;
        #pragma unroll
        for (int r = 0; r < 4; ++r) invd[r] = __shfl(linv, 4 * lg + r);
        #pragma unroll
        for (int dj = 0; dj < 2; ++dj) {
            int d = dj * 16 + l15;
            if (d >= HDz) continue;
            #pragma unroll
            for (int r = 0; r < 4; ++r) {
                int q = qb * 128 + w * 32 + mi * 16 + 4 * lg + r;
                if (q < Sz)
                    o[((size_t)b * Sp + q) * Kp + h * HDz + d] = f2b(O[mi][dj][r] * invd[r]);
            }
        }
    }
}

// ---------------- pool + fc_norm -> bf16 pooled ----------------
__global__ void pool_norm_k(const float* __restrict__ tok, const float* __restrict__ sc,
                            const float* __restrict__ bi, short* __restrict__ pooled) {
    int b = blockIdx.x;
    int t = threadIdx.x;
    float val = 0.f;
    if (t < Dz) {
        const float* base = tok + ((size_t)b * Sp + 1) * Dz + t;
        float s = 0.f;
        for (int si = 0; si < Nz; ++si) s += base[(size_t)si * Dz];
        val = s * (1.f / Nz);
    }
    __shared__ float red[8];
    float sum = val, sq = val * val;
    #pragma unroll
    for (int off = 32; off; off >>= 1) { sum += __shfl_xor(sum, off); sq += __shfl_xor(sq, off); }
    int wave = t >> 6, lane = t & 63;
    if (lane == 0) { red[wave] = sum; red[4 + wave] = sq; }
    __syncthreads();
    sum = red[0] + red[1] + red[2] + red[3];
    sq = red[4] + red[5] + red[6] + red[7];
    float mean = sum * (1.f / Dz);
    float var = sq * (1.f / Dz) - mean * mean;
    float rstd = rsqrtf(var + 1e-6f);
    if (t < Dz) pooled[(size_t)b * Kp + t] = f2b((val - mean) * rstd * sc[t] + bi[t]);
    else if (t < Kp) pooled[(size_t)b * Kp + t] = 0;
}

extern "C" void kernel_launch(void* const* d_in, const int* in_sizes, int n_in,
                              void* d_out, int out_size, void* d_ws, size_t ws_size,
                              hipStream_t stream) {
    const float* x        = (const float*)d_in[0];
    const float* conv_w   = (const float*)d_in[1];
    const float* conv_b   = (const float*)d_in[2];
    const float* cls_tok  = (const float*)d_in[3];
    const float* pos_emb  = (const float*)d_in[4];
    const float* ln1_s    = (const float*)d_in[5];
    const float* ln1_b    = (const float*)d_in[6];
    const float* qkv_w    = (const float*)d_in[7];
    const float* q_bias   = (const float*)d_in[8];
    const float* v_bias   = (const float*)d_in[9];
    const float* rpb      = (const float*)d_in[10];
    const float* proj_w   = (const float*)d_in[11];
    const float* proj_b   = (const float*)d_in[12];
    const float* ln2_s    = (const float*)d_in[13];
    const float* ln2_b    = (const float*)d_in[14];
    const float* fc1_w    = (const float*)d_in[15];
    const float* fc1_b    = (const float*)d_in[16];
    const float* fc2_w    = (const float*)d_in[17];
    const float* fc2_b    = (const float*)d_in[18];
    const float* fcn_s    = (const float*)d_in[19];
    const float* fcn_b    = (const float*)d_in[20];
    const float* head_w   = (const float*)d_in[21];
    const float* head_b   = (const float*)d_in[22];
    float* out = (float*)d_out;

    char* ws = (char*)d_ws;
    float* tok  = (float*)ws;  ws += (size_t)Mp * Dz * 4;
    short* xa   = (short*)ws;  ws += (size_t)Mp * Kp * 2;
    short* xb   = (short*)ws;  ws += (size_t)Mp * Kp * 2;
    short* xc   = (short*)ws;  ws += (size_t)Mp * Kp * 2;
    short* mid  = (short*)ws;  ws += (size_t)Mp * FFz * 2;
    short* Qb   = (short*)ws;  ws += (size_t)640 * 8192 * 2;
    short* Kb   = (short*)ws;  ws += (size_t)640 * 8192 * 2;
    short* Vtb  = (short*)ws;  ws += (size_t)640 * 8192 * 2;
    short* wq = (short*)ws;    ws += (size_t)Lz * 640 * Kp * 2;
    short* wp = (short*)ws;    ws += (size_t)Lz * 256 * Kp * 2;
    short* w1 = (short*)ws;    ws += (size_t)Lz * 896 * Kp * 2;
    short* w2 = (short*)ws;    ws += (size_t)Lz * 256 * FFz * 2;
    short* wh = (short*)ws;    ws += (size_t)1024 * Kp * 2;
    short* biasC = (short*)ws; ws += (size_t)Lz * BIASL * 2;
    short* xpb  = (short*)ws;  ws += (size_t)PEM * 64 * 2;
    short* wpe  = (short*)ws;  ws += (size_t)256 * 64 * 2;
    short* pooledb = (short*)ws; ws += (size_t)128 * Kp * 2;

    // xa pad rows feed K/V values -> must be finite (NaN there would poison softmax).
    hipMemsetAsync(xa, 0, (size_t)Mp * Kp * 2, stream);
    hipMemsetAsync(pooledb, 0, (size_t)128 * Kp * 2, stream);

    {
        int n;
        n = Lz * 640 * Kp;  cvt_pad_k<<<(n + 255) / 256, 256, 0, stream>>>(qkv_w, wq, 600, 200, 640, Kp, n);
        n = Lz * 256 * Kp;  cvt_pad_k<<<(n + 255) / 256, 256, 0, stream>>>(proj_w, wp, 200, 200, 256, Kp, n);
        n = Lz * 896 * Kp;  cvt_pad_k<<<(n + 255) / 256, 256, 0, stream>>>(fc1_w, w1, 800, 200, 896, Kp, n);
        n = Lz * 256 * FFz; cvt_pad_k<<<(n + 255) / 256, 256, 0, stream>>>(fc2_w, w2, 200, 800, 256, FFz, n);
        n = 1024 * Kp;      cvt_pad_k<<<(n + 255) / 256, 256, 0, stream>>>(head_w, wh, 1000, 200, 1024, Kp, n);
        n = 256 * 64;       cvt_pad_k<<<(n + 255) / 256, 256, 0, stream>>>(conv_w, wpe, 200, 50, 256, 64, n);
    }
    bias_pre4_k<<<dim3(640, Lz), 256, 0, stream>>>(rpb, biasC);

    xcvt_k<<<(PEM * 64) / 256, 256, 0, stream>>>(x, xpb);
    gemm8_k<4, 64, 128><<<4 * (PEM / 128), 256, 0, stream>>>(
        xpb, wpe, conv_b, nullptr, pos_emb, tok,
        nullptr, nullptr, nullptr, PEM, Dz, 64, 64, Dz, 4, PEM / 128);
    cls_k<<<Bz, 256, 0, stream>>>(cls_tok, pos_emb, tok);

    dim3 blk(256);
    ln_k<<<Mp / 4, blk, 0, stream>>>(tok, xa, ln1_s, ln1_b);
    for (int l = 0; l < Lz; ++l) {
        // BM=64: 1280 blocks, 37 KB LDS -> 4 blocks/CU (occupancy push)
        gemm8_k<1, 128, 64><<<5 * (Mp / 64), blk, 0, stream>>>(
            xa, wq + (size_t)l * 640 * Kp, q_bias + l * Dz, v_bias + l * Dz,
            nullptr, nullptr, Qb, Kb, Vtb,
            Mp, 600, Kp, Kp, 0, 5, Mp / 64);
        attn5_k<<<1280, blk, 0, stream>>>(Qb, Kb, Vtb, biasC + (size_t)l * BIASL, xb);
        gemm8_k<2, 64, 64><<<4 * (Mp / 64), blk, 0, stream>>>(
            xb, wp + (size_t)l * 256 * Kp, proj_b + l * Dz, nullptr,
            tok, tok, nullptr, nullptr, nullptr,
            Mp, Dz, Kp, Kp, Dz, 4, Mp / 64);
        ln_k<<<Mp / 4, blk, 0, stream>>>(tok, xc, ln2_s + l * Dz, ln2_b + l * Dz);
        gemm8_k<3, 128, 64><<<7 * (Mp / 64), blk, 0, stream>>>(
            xc, w1 + (size_t)l * 896 * Kp, fc1_b + l * FFz, nullptr,
            nullptr, mid, nullptr, nullptr, nullptr,
            Mp, FFz, Kp, Kp, FFz, 7, Mp / 64);
        gemm8_k<2, 64, 64><<<4 * (Mp / 64), blk, 0, stream>>>(
            mid, w2 + (size_t)l * 256 * FFz, fc2_b + l * Dz, nullptr,
            tok, tok, nullptr, nullptr, nullptr,
            Mp, Dz, FFz, FFz, Dz, 4, Mp / 64);
        ln_k<<<Mp / 4, blk, 0, stream>>>(tok, xa, ln1_s + (size_t)((l + 1) % Lz) * Dz,
                                         ln1_b + (size_t)((l + 1) % Lz) * Dz);
    }

    pool_norm_k<<<Bz, blk, 0, stream>>>(tok, fcn_s, fcn_b, pooledb);
    gemm8_k<0, 128, 128><<<8, blk, 0, stream>>>(
        pooledb, wh, head_b, nullptr, nullptr, out,
        nullptr, nullptr, nullptr, Bz, NCz, Kp, Kp, NCz, 8, 1);
}